// Round 6
// baseline (2961.283 us; speedup 1.0000x reference)
//
#include <hip/hip_runtime.h>
#include <hip/hip_bf16.h>

#define B_  8
#define D_  192
#define H_  64
#define W_  64
#define L_  4096
#define K_  4
#define N_  16
#define R_  6
#define C_  38   // R + 2N
#define CP  40   // padded x_dbl row (floats)
#define CL_ 64   // scan chunk length
#define NC_ 64   // number of chunks (L_/CL_)

using bf16 = __hip_bfloat16;
typedef float v2f __attribute__((ext_vector_type(2)));

static __device__ __forceinline__ float softplus_f(float x) {
    return fmaxf(x, 0.f) + __logf(1.f + __expf(-fabsf(x)));
}
static __device__ __forceinline__ float bflo(unsigned u) {
    return __uint_as_float(u << 16);
}
static __device__ __forceinline__ float bfhi(unsigned u) {
    return __uint_as_float(u & 0xffff0000u);
}

// ---------------------------------------------------------------------------
// Kernel 1: transpose x (B,D,L) -> xp0 (B,L,D) row-major scan order and
// xp1 (B,L1,D) col-major order (l1 = w*H + h), plus bf16 copies for k_proj.
// ---------------------------------------------------------------------------
__global__ __launch_bounds__(256) void k_transpose(const float* __restrict__ x,
                                                   float* __restrict__ xp0,
                                                   float* __restrict__ xp1,
                                                   bf16* __restrict__ xp0b,
                                                   bf16* __restrict__ xp1b) {
    __shared__ float tile[32][33];
    int bi = blockIdx.x;
    int pg = bi & 127;          // L/32 tiles
    int dg = (bi >> 7) % 6;     // D/32 tiles
    int b  = bi / (128 * 6);
    int tx = threadIdx.x & 31;
    int ty = threadIdx.x >> 5;  // 0..7
    size_t xbase = (size_t)b * D_ * L_;
    #pragma unroll
    for (int i = 0; i < 4; i++) {
        int d = dg * 32 + ty + i * 8;
        tile[ty + i * 8][tx] = x[xbase + (size_t)d * L_ + pg * 32 + tx];
    }
    __syncthreads();
    #pragma unroll
    for (int i = 0; i < 4; i++) {
        int p = pg * 32 + ty + i * 8;
        float v = tile[tx][ty + i * 8];
        bf16 vb = __float2bfloat16(v);
        int d = dg * 32 + tx;
        size_t o0 = ((size_t)b * L_ + p) * D_ + d;
        xp0[o0] = v;  xp0b[o0] = vb;
        int hh = p >> 6, ww = p & 63;
        int r = ww * 64 + hh;   // l1 index
        size_t o1 = ((size_t)b * L_ + r) * D_ + d;
        xp1[o1] = v;  xp1b[o1] = vb;
    }
}

// ---------------------------------------------------------------------------
// Kernel 2: projection x_dbl[b,k,l,c] = sum_d xs[b,k,d,l] * W[k,c,d]
// Block = 64 positions x 38 channels. Wave = channel-quarter (wave-uniform,
// W loads scalarize to s_load); lane = position (x from LDS, b128 per group).
// ---------------------------------------------------------------------------
__global__ __launch_bounds__(256) void k_proj(const bf16* __restrict__ xp0b,
                                              const bf16* __restrict__ xp1b,
                                              const float* __restrict__ Wp,   // (K,38,192)
                                              float* __restrict__ xdbl) {     // (B,K,L,CP)
    __shared__ __align__(16) unsigned short xt[64 * 200]; // 25.6 KB, stride 200 bf16
    int blk  = blockIdx.x;
    int tile = blk & 63;            // L/64 tiles
    int bk   = blk >> 6;
    int k    = bk & 3;
    int b    = bk >> 2;
    const bf16* xpb = (k & 1) ? xp1b : xp0b;
    int g0 = (k < 2) ? tile * 64 : (L_ - 64 - tile * 64);

    const uint4* src = (const uint4*)(xpb + ((size_t)b * L_ + g0) * D_);
    for (int i = threadIdx.x; i < 1536; i += 256) {
        uint4 v = src[i];
        int row = i / 24, cg = i % 24;
        *((uint4*)(xt + row * 200 + cg * 8)) = v;
    }
    __syncthreads();

    int lane = threadIdx.x & 63;
    int wv   = __builtin_amdgcn_readfirstlane((int)(threadIdx.x >> 6)); // 0..3
    int c0   = wv * 10;
    int l    = tile * 64 + lane;
    int lrow = (k < 2) ? lane : (63 - lane);

    const unsigned short* xrow = xt + lrow * 200;

    float acc[10];
    #pragma unroll
    for (int ci = 0; ci < 10; ci++) acc[ci] = 0.f;

    for (int kk = 0; kk < 24; kk++) {       // 24 groups of 8 d-channels
        uint4 xv = *((const uint4*)(xrow + kk * 8));
        float xf0 = bflo(xv.x), xf1 = bfhi(xv.x);
        float xf2 = bflo(xv.y), xf3 = bfhi(xv.y);
        float xf4 = bflo(xv.z), xf5 = bfhi(xv.z);
        float xf6 = bflo(xv.w), xf7 = bfhi(xv.w);
        #pragma unroll
        for (int ci = 0; ci < 10; ci++) {
            int c = c0 + ci; if (c > 37) c = 37;     // wave 3: dup of c37 (harmless)
            const float* w = Wp + ((size_t)k * C_ + c) * D_ + kk * 8;  // uniform -> s_load
            float4 w0 = *((const float4*)w);
            float4 w1 = *((const float4*)(w + 4));
            acc[ci] = fmaf(xf0, w0.x, acc[ci]); acc[ci] = fmaf(xf1, w0.y, acc[ci]);
            acc[ci] = fmaf(xf2, w0.z, acc[ci]); acc[ci] = fmaf(xf3, w0.w, acc[ci]);
            acc[ci] = fmaf(xf4, w1.x, acc[ci]); acc[ci] = fmaf(xf5, w1.y, acc[ci]);
            acc[ci] = fmaf(xf6, w1.z, acc[ci]); acc[ci] = fmaf(xf7, w1.w, acc[ci]);
        }
    }
    float* orow = xdbl + ((size_t)bk * L_ + l) * CP;
    #pragma unroll
    for (int ci = 0; ci < 10; ci++) {
        int c = c0 + ci; if (c > 37) c = 37;
        orow[c] = acc[ci];
    }
}

// ---------------------------------------------------------------------------
// Kernel 3: fused single-pass chained scan.
// Ticket-ordered virtual block id -> (bk, chunk). Loop1: local scan (B-part,
// h=0). Wait on predecessor's inclusive state (device-scope flag), combine
// h_out = P*h_in + Hloc (all f32), publish, then emit loop from true h_in
// (xdbl/u L2-warm from loop1).
// ---------------------------------------------------------------------------
__global__ __launch_bounds__(192) void k_scan(const float* __restrict__ xdbl,
                                              const float* __restrict__ xp0,
                                              const float* __restrict__ xp1,
                                              const float* __restrict__ dtw,   // (K,D,R)
                                              const float* __restrict__ dtb,   // (K,D)
                                              const float* __restrict__ Alog,  // (K*D,N)
                                              const float* __restrict__ Dsk,   // (K*D,)
                                              float* __restrict__ state,       // (BK*NC, N, D) f32
                                              unsigned int* __restrict__ flags,
                                              unsigned int* __restrict__ ticket,
                                              bf16* __restrict__ ys) {         // (B,K,L,D)
    __shared__ int s_vid;
    if (threadIdx.x == 0) s_vid = (int)atomicAdd(ticket, 1u);
    __syncthreads();
    int vid = s_vid;
    int c   = vid & (NC_ - 1);
    int bk  = vid >> 6;          // NC_ = 64
    int k   = bk & 3;
    int b   = bk >> 2;
    int d   = threadIdx.x;

    v2f A2[8];     // A * log2(e) pairs, for exp2
    #pragma unroll
    for (int i = 0; i < 8; i++) {
        A2[i].x = -__expf(Alog[((size_t)(k * D_ + d)) * N_ + 2*i])   * 1.44269504f;
        A2[i].y = -__expf(Alog[((size_t)(k * D_ + d)) * N_ + 2*i+1]) * 1.44269504f;
    }
    float wr[R_];
    #pragma unroll
    for (int r = 0; r < R_; r++) wr[r] = dtw[(k * D_ + d) * R_ + r];
    float bias = dtb[k * D_ + d];
    float DsV  = Dsk[k * D_ + d];
    const float* xp = (k & 1) ? xp1 : xp0;

    int l0  = c * CL_;
    int lu0 = (k < 2) ? l0 : (L_ - 1 - l0);
    int ustep = (k < 2) ? D_ : -D_;
    const float* rb = xdbl + ((size_t)bk * L_ + l0) * CP;

    // ---- loop 1: local scan from h=0 (B-part only), accumulate S
    v2f h[8];
    #pragma unroll
    for (int i = 0; i < 8; i++) { h[i].x = 0.f; h[i].y = 0.f; }
    float S = 0.f;
    {
        const float* up = xp + ((size_t)b * L_ + lu0) * D_ + d;
        #pragma unroll 2
        for (int s = 0; s < CL_; s++) {
            const float4* r4 = (const float4*)(rb + s * CP);   // block-uniform -> s_load
            float4 q0 = r4[0], q1 = r4[1], q2 = r4[2], q3 = r4[3], q4 = r4[4], q5 = r4[5];
            float dpre = bias + wr[0]*q0.x + wr[1]*q0.y + wr[2]*q0.z + wr[3]*q0.w
                              + wr[4]*q1.x + wr[5]*q1.y;
            float delta = softplus_f(dpre);
            float u  = *up;  up += ustep;
            float du = delta * u;
            S += delta;
            v2f Bv[8] = {{q1.z,q1.w},{q2.x,q2.y},{q2.z,q2.w},{q3.x,q3.y},
                         {q3.z,q3.w},{q4.x,q4.y},{q4.z,q4.w},{q5.x,q5.y}};
            #pragma unroll
            for (int i = 0; i < 8; i++) {
                v2f t = A2[i] * delta;
                v2f dA;
                dA.x = __builtin_amdgcn_exp2f(t.x);
                dA.y = __builtin_amdgcn_exp2f(t.y);
                h[i] = dA * h[i] + Bv[i] * du;
            }
        }
    }

    // ---- receive h_in from predecessor (same bk, chunk c-1)
    v2f hin[8];
    if (c > 0) {
        if (threadIdx.x == 0) {
            while (__hip_atomic_load(&flags[vid - 1], __ATOMIC_ACQUIRE,
                                     __HIP_MEMORY_SCOPE_AGENT) == 0u)
                __builtin_amdgcn_s_sleep(1);
            __threadfence();
        }
        __syncthreads();
        const float* sp = state + (size_t)(vid - 1) * (D_ * N_);
        #pragma unroll
        for (int i = 0; i < 8; i++) {
            hin[i].x = sp[(2*i)   * D_ + d];
            hin[i].y = sp[(2*i+1) * D_ + d];
        }
    } else {
        #pragma unroll
        for (int i = 0; i < 8; i++) { hin[i].x = 0.f; hin[i].y = 0.f; }
    }

    // ---- combine: h_out = exp(A*S) * h_in + h_loc ; publish
    #pragma unroll
    for (int i = 0; i < 8; i++) {
        v2f t = A2[i] * S;
        v2f P;
        P.x = __builtin_amdgcn_exp2f(t.x);
        P.y = __builtin_amdgcn_exp2f(t.y);
        h[i] = P * hin[i] + h[i];
    }
    if (c < NC_ - 1) {
        float* st = state + (size_t)vid * (D_ * N_);
        #pragma unroll
        for (int i = 0; i < 8; i++) {
            st[(2*i)   * D_ + d] = h[i].x;
            st[(2*i+1) * D_ + d] = h[i].y;
        }
        __syncthreads();
        if (threadIdx.x == 0) {
            __threadfence();
            __hip_atomic_store(&flags[vid], 1u, __ATOMIC_RELEASE,
                               __HIP_MEMORY_SCOPE_AGENT);
        }
    }

    // ---- loop 2: emit from true h_in (xdbl/u L2-warm)
    #pragma unroll
    for (int i = 0; i < 8; i++) h[i] = hin[i];
    {
        const float* up = xp + ((size_t)b * L_ + lu0) * D_ + d;
        bf16* yp = ys + ((size_t)bk * L_ + l0) * D_ + d;
        #pragma unroll 2
        for (int s = 0; s < CL_; s++) {
            const float4* r4 = (const float4*)(rb + s * CP);
            float4 q0 = r4[0], q1 = r4[1], q2 = r4[2], q3 = r4[3], q4 = r4[4];
            float4 q5 = r4[5], q6 = r4[6], q7 = r4[7], q8 = r4[8], q9 = r4[9];
            float dpre = bias + wr[0]*q0.x + wr[1]*q0.y + wr[2]*q0.z + wr[3]*q0.w
                              + wr[4]*q1.x + wr[5]*q1.y;
            float delta = softplus_f(dpre);
            float u  = *up;  up += ustep;
            float du = delta * u;
            v2f Bv[8] = {{q1.z,q1.w},{q2.x,q2.y},{q2.z,q2.w},{q3.x,q3.y},
                         {q3.z,q3.w},{q4.x,q4.y},{q4.z,q4.w},{q5.x,q5.y}};
            v2f Cv[8] = {{q5.z,q5.w},{q6.x,q6.y},{q6.z,q6.w},{q7.x,q7.y},
                         {q7.z,q7.w},{q8.x,q8.y},{q8.z,q8.w},{q9.x,q9.y}};
            v2f y2; y2.x = 0.f; y2.y = 0.f;
            #pragma unroll
            for (int i = 0; i < 8; i++) {
                v2f t = A2[i] * delta;
                v2f dA;
                dA.x = __builtin_amdgcn_exp2f(t.x);
                dA.y = __builtin_amdgcn_exp2f(t.y);
                h[i] = dA * h[i] + Bv[i] * du;
                y2   = y2 + h[i] * Cv[i];
            }
            float y = y2.x + y2.y;
            *yp = __float2bfloat16(y + u * DsV);
            yp += D_;
        }
    }
}

// ---------------------------------------------------------------------------
// Kernel 4: cross-merge (4 directions) + LayerNorm over D, output (B,H,W,D)
// ---------------------------------------------------------------------------
__global__ __launch_bounds__(192) void k_merge_ln(const bf16* __restrict__ ys,
                                                  const float* __restrict__ gw,
                                                  const float* __restrict__ gb,
                                                  float* __restrict__ out) {
    int p = blockIdx.x & (L_ - 1);
    int b = blockIdx.x >> 12;     // L_ = 4096
    int d = threadIdx.x;
    int hh = p >> 6, ww = p & 63;
    int l1 = ww * 64 + hh;
    size_t base = (size_t)b * K_ * L_ * D_;
    float v = __bfloat162float(ys[base + ((size_t)0 * L_ + p) * D_ + d])
            + __bfloat162float(ys[base + ((size_t)2 * L_ + (L_ - 1 - p)) * D_ + d])
            + __bfloat162float(ys[base + ((size_t)1 * L_ + l1) * D_ + d])
            + __bfloat162float(ys[base + ((size_t)3 * L_ + (L_ - 1 - l1)) * D_ + d]);
    float s1 = v, s2 = v * v;
    #pragma unroll
    for (int off = 32; off; off >>= 1) {
        s1 += __shfl_down(s1, off);
        s2 += __shfl_down(s2, off);
    }
    __shared__ float aS[3], aQ[3];
    int wid = d >> 6, lane = d & 63;
    if (lane == 0) { aS[wid] = s1; aQ[wid] = s2; }
    __syncthreads();
    float ts1 = aS[0] + aS[1] + aS[2];
    float ts2 = aQ[0] + aQ[1] + aQ[2];
    float mean = ts1 * (1.f / 192.f);
    float var  = ts2 * (1.f / 192.f) - mean * mean;
    float inv  = rsqrtf(var + 1e-5f);
    out[((size_t)b * L_ + p) * D_ + d] = (v - mean) * inv * gw[d] + gb[d];
}

// ---------------------------------------------------------------------------
extern "C" void kernel_launch(void* const* d_in, const int* in_sizes, int n_in,
                              void* d_out, int out_size, void* d_ws, size_t ws_size,
                              hipStream_t stream) {
    const float* x    = (const float*)d_in[0];
    const float* Wp   = (const float*)d_in[1];
    const float* dtw  = (const float*)d_in[2];
    const float* dtb  = (const float*)d_in[3];
    const float* Alog = (const float*)d_in[4];
    const float* Dsk  = (const float*)d_in[5];
    const float* gw   = (const float*)d_in[6];
    const float* gb   = (const float*)d_in[7];
    float* out = (float*)d_out;

    char* ws = (char*)d_ws;
    const size_t S1  = (size_t)B_ * L_ * D_ * 4;            // 25.2 MB (xp0/xp1)
    const size_t S1b = (size_t)B_ * L_ * D_ * 2;            // 12.6 MB (xp0b/xp1b)
    const size_t Sx  = (size_t)B_ * K_ * L_ * CP * 4;       // 21.0 MB (xdbl)
    const size_t Sst = (size_t)B_ * K_ * NC_ * D_ * N_ * 4; // 25.2 MB (chain state f32)
    const size_t Sy  = (size_t)B_ * K_ * L_ * D_ * 2;       // 50.3 MB (ys)
    const size_t Sfl = (size_t)B_ * K_ * NC_ * 4 + 16;      // flags + ticket
    char* p = ws;
    float* xp0   = (float*)p;  p += S1;
    float* xp1   = (float*)p;  p += S1;
    bf16*  xp0b  = (bf16*)p;   p += S1b;
    bf16*  xp1b  = (bf16*)p;   p += S1b;
    float* xdbl  = (float*)p;  p += Sx;
    float* state = (float*)p;  p += Sst;
    bf16*  ys    = (bf16*)p;   p += Sy;
    unsigned int* flags  = (unsigned int*)p;
    unsigned int* ticket = (unsigned int*)(p + Sfl - 16);
    // total ws use: ~172 MB

    hipMemsetAsync(flags, 0, Sfl, stream);
    k_transpose<<<B_ * 6 * 128, 256, 0, stream>>>(x, xp0, xp1, xp0b, xp1b);
    k_proj<<<B_ * K_ * (L_ / 64), 256, 0, stream>>>(xp0b, xp1b, Wp, xdbl);
    k_scan<<<B_ * K_ * NC_, 192, 0, stream>>>(xdbl, xp0, xp1, dtw, dtb, Alog, Dsk,
                                              state, flags, ticket, ys);
    k_merge_ln<<<B_ * L_, 192, 0, stream>>>(ys, gw, gb, out);
}

// Round 7
// 518.253 us; speedup vs baseline: 5.7140x; 5.7140x over previous
//
#include <hip/hip_runtime.h>
#include <hip/hip_bf16.h>

#define B_  8
#define D_  192
#define H_  64
#define W_  64
#define L_  4096
#define K_  4
#define N_  16
#define R_  6
#define C_  38   // R + 2N
#define CP  40   // padded x_dbl row (floats)
#define CL_ 64   // scan chunk length
#define NC_ 64   // number of chunks (L_/CL_)

using bf16 = __hip_bfloat16;
typedef float v2f __attribute__((ext_vector_type(2)));

static __device__ __forceinline__ float softplus_f(float x) {
    return fmaxf(x, 0.f) + __logf(1.f + __expf(-fabsf(x)));
}
static __device__ __forceinline__ float bflo(unsigned u) {
    return __uint_as_float(u << 16);
}
static __device__ __forceinline__ float bfhi(unsigned u) {
    return __uint_as_float(u & 0xffff0000u);
}

// ---------------------------------------------------------------------------
// Kernel 1: transpose x (B,D,L) -> xp0 (B,L,D) row-major scan order and
// xp1 (B,L1,D) col-major order (l1 = w*H + h), plus bf16 copies for k_proj.
// ---------------------------------------------------------------------------
__global__ __launch_bounds__(256) void k_transpose(const float* __restrict__ x,
                                                   float* __restrict__ xp0,
                                                   float* __restrict__ xp1,
                                                   bf16* __restrict__ xp0b,
                                                   bf16* __restrict__ xp1b) {
    __shared__ float tile[32][33];
    int bi = blockIdx.x;
    int pg = bi & 127;          // L/32 tiles
    int dg = (bi >> 7) % 6;     // D/32 tiles
    int b  = bi / (128 * 6);
    int tx = threadIdx.x & 31;
    int ty = threadIdx.x >> 5;  // 0..7
    size_t xbase = (size_t)b * D_ * L_;
    #pragma unroll
    for (int i = 0; i < 4; i++) {
        int d = dg * 32 + ty + i * 8;
        tile[ty + i * 8][tx] = x[xbase + (size_t)d * L_ + pg * 32 + tx];
    }
    __syncthreads();
    #pragma unroll
    for (int i = 0; i < 4; i++) {
        int p = pg * 32 + ty + i * 8;
        float v = tile[tx][ty + i * 8];
        bf16 vb = __float2bfloat16(v);
        int d = dg * 32 + tx;
        size_t o0 = ((size_t)b * L_ + p) * D_ + d;
        xp0[o0] = v;  xp0b[o0] = vb;
        int hh = p >> 6, ww = p & 63;
        int r = ww * 64 + hh;   // l1 index
        size_t o1 = ((size_t)b * L_ + r) * D_ + d;
        xp1[o1] = v;  xp1b[o1] = vb;
    }
}

// ---------------------------------------------------------------------------
// Kernel 2: projection x_dbl[b,k,l,c] = sum_d xs[b,k,d,l] * W[k,c,d]
// Block = 64 positions x 38 channels. Wave = channel-quarter (wave-uniform,
// W loads scalarize to s_load); lane = position (x from LDS, b128 per group).
// ---------------------------------------------------------------------------
__global__ __launch_bounds__(256) void k_proj(const bf16* __restrict__ xp0b,
                                              const bf16* __restrict__ xp1b,
                                              const float* __restrict__ Wp,   // (K,38,192)
                                              float* __restrict__ xdbl) {     // (B,K,L,CP)
    __shared__ __align__(16) unsigned short xt[64 * 200]; // 25.6 KB, stride 200 bf16
    int blk  = blockIdx.x;
    int tile = blk & 63;            // L/64 tiles
    int bk   = blk >> 6;
    int k    = bk & 3;
    int b    = bk >> 2;
    const bf16* xpb = (k & 1) ? xp1b : xp0b;
    int g0 = (k < 2) ? tile * 64 : (L_ - 64 - tile * 64);

    const uint4* src = (const uint4*)(xpb + ((size_t)b * L_ + g0) * D_);
    for (int i = threadIdx.x; i < 1536; i += 256) {
        uint4 v = src[i];
        int row = i / 24, cg = i % 24;
        *((uint4*)(xt + row * 200 + cg * 8)) = v;
    }
    __syncthreads();

    int lane = threadIdx.x & 63;
    int wv   = __builtin_amdgcn_readfirstlane((int)(threadIdx.x >> 6)); // 0..3
    int c0   = wv * 10;
    int l    = tile * 64 + lane;
    int lrow = (k < 2) ? lane : (63 - lane);

    const unsigned short* xrow = xt + lrow * 200;

    float acc[10];
    #pragma unroll
    for (int ci = 0; ci < 10; ci++) acc[ci] = 0.f;

    for (int kk = 0; kk < 24; kk++) {       // 24 groups of 8 d-channels
        uint4 xv = *((const uint4*)(xrow + kk * 8));
        float xf0 = bflo(xv.x), xf1 = bfhi(xv.x);
        float xf2 = bflo(xv.y), xf3 = bfhi(xv.y);
        float xf4 = bflo(xv.z), xf5 = bfhi(xv.z);
        float xf6 = bflo(xv.w), xf7 = bfhi(xv.w);
        #pragma unroll
        for (int ci = 0; ci < 10; ci++) {
            int c = c0 + ci; if (c > 37) c = 37;     // wave 3: dup of c37 (harmless)
            const float* w = Wp + ((size_t)k * C_ + c) * D_ + kk * 8;  // uniform -> s_load
            float4 w0 = *((const float4*)w);
            float4 w1 = *((const float4*)(w + 4));
            acc[ci] = fmaf(xf0, w0.x, acc[ci]); acc[ci] = fmaf(xf1, w0.y, acc[ci]);
            acc[ci] = fmaf(xf2, w0.z, acc[ci]); acc[ci] = fmaf(xf3, w0.w, acc[ci]);
            acc[ci] = fmaf(xf4, w1.x, acc[ci]); acc[ci] = fmaf(xf5, w1.y, acc[ci]);
            acc[ci] = fmaf(xf6, w1.z, acc[ci]); acc[ci] = fmaf(xf7, w1.w, acc[ci]);
        }
    }
    float* orow = xdbl + ((size_t)bk * L_ + l) * CP;
    #pragma unroll
    for (int ci = 0; ci < 10; ci++) {
        int c = c0 + ci; if (c > 37) c = 37;
        orow[c] = acc[ci];
    }
}

// ---------------------------------------------------------------------------
// Kernel 3 (pass 1): per-chunk partial scan from h=0. Packed f32 math; xdbl
// row pointer forced into VGPR so loads are per-lane dwordx4 broadcasts —
// float4 results land in even-aligned VGPR quads, v2f pairs alias them with
// zero v_mov repacks (the round-5 defect).
// ---------------------------------------------------------------------------
__global__ __launch_bounds__(192) void k_pass1(const float* __restrict__ xdbl,
                                               const float* __restrict__ xp0,
                                               const float* __restrict__ xp1,
                                               const float* __restrict__ dtw,   // (K,D,R)
                                               const float* __restrict__ dtb,   // (K,D)
                                               const float* __restrict__ Alog,  // (K*D,N)
                                               bf16* __restrict__ Pst,
                                               bf16* __restrict__ Hloc) {
    int blk = blockIdx.x;
    int c   = blk & (NC_ - 1);
    int bk  = blk >> 6;
    int k   = bk & 3;
    int b   = bk >> 2;
    int d   = threadIdx.x;

    v2f A2[8];     // A * log2(e) pairs, for exp2
    #pragma unroll
    for (int i = 0; i < 8; i++) {
        A2[i].x = -__expf(Alog[((size_t)(k * D_ + d)) * N_ + 2*i])   * 1.44269504f;
        A2[i].y = -__expf(Alog[((size_t)(k * D_ + d)) * N_ + 2*i+1]) * 1.44269504f;
    }
    float wr[R_];
    #pragma unroll
    for (int r = 0; r < R_; r++) wr[r] = dtw[(k * D_ + d) * R_ + r];
    float bias = dtb[k * D_ + d];
    const float* xp = (k & 1) ? xp1 : xp0;

    int l0  = c * CL_;
    int lu0 = (k < 2) ? l0 : (L_ - 1 - l0);
    int ustep = (k < 2) ? D_ : -D_;
    const float* up = xp + ((size_t)b * L_ + lu0) * D_ + d;

    v2f h[8];
    #pragma unroll
    for (int i = 0; i < 8; i++) { h[i].x = 0.f; h[i].y = 0.f; }
    float S = 0.f;
    const float* rb = xdbl + ((size_t)bk * L_ + l0) * CP;
    asm("" : "+v"(rb));   // defeat uniformity analysis -> per-lane vector loads

    #pragma unroll 2
    for (int s = 0; s < CL_; s++) {
        const float4* r4 = (const float4*)rb;
        float4 q0 = r4[0], q1 = r4[1], q2 = r4[2], q3 = r4[3], q4 = r4[4], q5 = r4[5];
        rb += CP;
        float dpre = bias + wr[0]*q0.x + wr[1]*q0.y + wr[2]*q0.z + wr[3]*q0.w
                          + wr[4]*q1.x + wr[5]*q1.y;
        float delta = softplus_f(dpre);
        float u  = *up;  up += ustep;
        float du = delta * u;
        S += delta;
        v2f Bv[8] = {{q1.z,q1.w},{q2.x,q2.y},{q2.z,q2.w},{q3.x,q3.y},
                     {q3.z,q3.w},{q4.x,q4.y},{q4.z,q4.w},{q5.x,q5.y}};
        #pragma unroll
        for (int i = 0; i < 8; i++) {
            v2f t = A2[i] * delta;
            v2f dA;
            dA.x = __builtin_amdgcn_exp2f(t.x);
            dA.y = __builtin_amdgcn_exp2f(t.y);
            h[i] = dA * h[i] + Bv[i] * du;
        }
    }
    size_t o = ((size_t)blk * D_ + d) * N_;   // blk == bk*NC_ + c
    #pragma unroll
    for (int i = 0; i < 8; i++) {
        v2f t = A2[i] * S;
        Pst[o + 2*i]   = __float2bfloat16(__builtin_amdgcn_exp2f(t.x));
        Pst[o + 2*i+1] = __float2bfloat16(__builtin_amdgcn_exp2f(t.y));
        Hloc[o + 2*i]   = __float2bfloat16(h[i].x);
        Hloc[o + 2*i+1] = __float2bfloat16(h[i].y);
    }
}

// ---------------------------------------------------------------------------
// Kernel 4 (pass 2): chunk-prefix scan over NC_ chunks per (b,k,d,n).
// ---------------------------------------------------------------------------
__global__ __launch_bounds__(256) void k_pass2(const bf16* __restrict__ Pst,
                                               const bf16* __restrict__ Hloc,
                                               bf16* __restrict__ Hin) {
    int idx = blockIdx.x * 256 + threadIdx.x;   // over B*K*D*N
    int bk  = idx / (D_ * N_);
    int dn  = idx % (D_ * N_);
    float hh = 0.f;
    for (int c = 0; c < NC_; c++) {
        size_t o = ((size_t)bk * NC_ + c) * (D_ * N_) + dn;
        Hin[o] = __float2bfloat16(hh);
        hh = __bfloat162float(Pst[o]) * hh + __bfloat162float(Hloc[o]);
    }
}

// ---------------------------------------------------------------------------
// Kernel 5 (pass 3): recompute chunk scan with true h0, emit
// ys[b,k,l,d] = C_l . h_l + u * Ds (bf16). Per-lane vector loads + packed math.
// ---------------------------------------------------------------------------
__global__ __launch_bounds__(192) void k_pass3(const float* __restrict__ xdbl,
                                               const float* __restrict__ xp0,
                                               const float* __restrict__ xp1,
                                               const float* __restrict__ dtw,
                                               const float* __restrict__ dtb,
                                               const float* __restrict__ Alog,
                                               const float* __restrict__ Dsk,  // (K*D,)
                                               const bf16* __restrict__ Hin,
                                               bf16* __restrict__ ys) {        // (B,K,L,D)
    int blk = blockIdx.x;
    int c   = blk & (NC_ - 1);
    int bk  = blk >> 6;
    int k   = bk & 3;
    int b   = bk >> 2;
    int d   = threadIdx.x;

    v2f A2[8];
    #pragma unroll
    for (int i = 0; i < 8; i++) {
        A2[i].x = -__expf(Alog[((size_t)(k * D_ + d)) * N_ + 2*i])   * 1.44269504f;
        A2[i].y = -__expf(Alog[((size_t)(k * D_ + d)) * N_ + 2*i+1]) * 1.44269504f;
    }
    float wr[R_];
    #pragma unroll
    for (int r = 0; r < R_; r++) wr[r] = dtw[(k * D_ + d) * R_ + r];
    float bias = dtb[k * D_ + d];
    float DsV  = Dsk[k * D_ + d];
    const float* xp = (k & 1) ? xp1 : xp0;

    int l0  = c * CL_;
    int lu0 = (k < 2) ? l0 : (L_ - 1 - l0);
    int ustep = (k < 2) ? D_ : -D_;
    const float* up = xp + ((size_t)b * L_ + lu0) * D_ + d;
    bf16* yp = ys + ((size_t)bk * L_ + l0) * D_ + d;

    v2f h[8];
    size_t o = ((size_t)blk * D_ + d) * N_;
    #pragma unroll
    for (int i = 0; i < 8; i++) {
        h[i].x = __bfloat162float(Hin[o + 2*i]);
        h[i].y = __bfloat162float(Hin[o + 2*i+1]);
    }

    const float* rb = xdbl + ((size_t)bk * L_ + l0) * CP;
    asm("" : "+v"(rb));   // defeat uniformity analysis -> per-lane vector loads

    #pragma unroll 2
    for (int s = 0; s < CL_; s++) {
        const float4* r4 = (const float4*)rb;
        float4 q0 = r4[0], q1 = r4[1], q2 = r4[2], q3 = r4[3], q4 = r4[4];
        float4 q5 = r4[5], q6 = r4[6], q7 = r4[7], q8 = r4[8], q9 = r4[9];
        rb += CP;
        float dpre = bias + wr[0]*q0.x + wr[1]*q0.y + wr[2]*q0.z + wr[3]*q0.w
                          + wr[4]*q1.x + wr[5]*q1.y;
        float delta = softplus_f(dpre);
        float u  = *up;  up += ustep;
        float du = delta * u;
        v2f Bv[8] = {{q1.z,q1.w},{q2.x,q2.y},{q2.z,q2.w},{q3.x,q3.y},
                     {q3.z,q3.w},{q4.x,q4.y},{q4.z,q4.w},{q5.x,q5.y}};
        v2f Cv[8] = {{q5.z,q5.w},{q6.x,q6.y},{q6.z,q6.w},{q7.x,q7.y},
                     {q7.z,q7.w},{q8.x,q8.y},{q8.z,q8.w},{q9.x,q9.y}};
        v2f y2; y2.x = 0.f; y2.y = 0.f;
        #pragma unroll
        for (int i = 0; i < 8; i++) {
            v2f t = A2[i] * delta;
            v2f dA;
            dA.x = __builtin_amdgcn_exp2f(t.x);
            dA.y = __builtin_amdgcn_exp2f(t.y);
            h[i] = dA * h[i] + Bv[i] * du;
            y2   = y2 + h[i] * Cv[i];
        }
        float y = y2.x + y2.y;
        *yp = __float2bfloat16(y + u * DsV);
        yp += D_;
    }
}

// ---------------------------------------------------------------------------
// Kernel 6: cross-merge (4 directions) + LayerNorm over D, output (B,H,W,D)
// ---------------------------------------------------------------------------
__global__ __launch_bounds__(192) void k_merge_ln(const bf16* __restrict__ ys,
                                                  const float* __restrict__ gw,
                                                  const float* __restrict__ gb,
                                                  float* __restrict__ out) {
    int p = blockIdx.x & (L_ - 1);
    int b = blockIdx.x >> 12;     // L_ = 4096
    int d = threadIdx.x;
    int hh = p >> 6, ww = p & 63;
    int l1 = ww * 64 + hh;
    size_t base = (size_t)b * K_ * L_ * D_;
    float v = __bfloat162float(ys[base + ((size_t)0 * L_ + p) * D_ + d])
            + __bfloat162float(ys[base + ((size_t)2 * L_ + (L_ - 1 - p)) * D_ + d])
            + __bfloat162float(ys[base + ((size_t)1 * L_ + l1) * D_ + d])
            + __bfloat162float(ys[base + ((size_t)3 * L_ + (L_ - 1 - l1)) * D_ + d]);
    float s1 = v, s2 = v * v;
    #pragma unroll
    for (int off = 32; off; off >>= 1) {
        s1 += __shfl_down(s1, off);
        s2 += __shfl_down(s2, off);
    }
    __shared__ float aS[3], aQ[3];
    int wid = d >> 6, lane = d & 63;
    if (lane == 0) { aS[wid] = s1; aQ[wid] = s2; }
    __syncthreads();
    float ts1 = aS[0] + aS[1] + aS[2];
    float ts2 = aQ[0] + aQ[1] + aQ[2];
    float mean = ts1 * (1.f / 192.f);
    float var  = ts2 * (1.f / 192.f) - mean * mean;
    float inv  = rsqrtf(var + 1e-5f);
    out[((size_t)b * L_ + p) * D_ + d] = (v - mean) * inv * gw[d] + gb[d];
}

// ---------------------------------------------------------------------------
extern "C" void kernel_launch(void* const* d_in, const int* in_sizes, int n_in,
                              void* d_out, int out_size, void* d_ws, size_t ws_size,
                              hipStream_t stream) {
    const float* x    = (const float*)d_in[0];
    const float* Wp   = (const float*)d_in[1];
    const float* dtw  = (const float*)d_in[2];
    const float* dtb  = (const float*)d_in[3];
    const float* Alog = (const float*)d_in[4];
    const float* Dsk  = (const float*)d_in[5];
    const float* gw   = (const float*)d_in[6];
    const float* gb   = (const float*)d_in[7];
    float* out = (float*)d_out;

    char* ws = (char*)d_ws;
    const size_t S1  = (size_t)B_ * L_ * D_ * 4;            // 25.2 MB (xp0/xp1)
    const size_t S1b = (size_t)B_ * L_ * D_ * 2;            // 12.6 MB (xp0b/xp1b)
    const size_t Sx  = (size_t)B_ * K_ * L_ * CP * 4;       // 21.0 MB (xdbl)
    const size_t Ss  = (size_t)B_ * K_ * NC_ * D_ * N_ * 2; // 12.6 MB (P/Hloc/Hin)
    char* p = ws;
    float* xp0  = (float*)p;  p += S1;
    float* xp1  = (float*)p;  p += S1;
    bf16*  xp0b = (bf16*)p;   p += S1b;
    bf16*  xp1b = (bf16*)p;   p += S1b;
    float* xdbl = (float*)p;  p += Sx;
    bf16*  Pst  = (bf16*)p;   p += Ss;
    bf16*  Hloc = (bf16*)p;   p += Ss;
    bf16*  Hin  = (bf16*)p;   p += Ss;
    bf16*  ys   = (bf16*)p;   // 50.3 MB; total ~185 MB

    k_transpose<<<B_ * 6 * 128, 256, 0, stream>>>(x, xp0, xp1, xp0b, xp1b);
    k_proj<<<B_ * K_ * (L_ / 64), 256, 0, stream>>>(xp0b, xp1b, Wp, xdbl);
    k_pass1<<<B_ * K_ * NC_, 192, 0, stream>>>(xdbl, xp0, xp1, dtw, dtb, Alog, Pst, Hloc);
    k_pass2<<<(B_ * K_ * D_ * N_) / 256, 256, 0, stream>>>(Pst, Hloc, Hin);
    k_pass3<<<B_ * K_ * NC_, 192, 0, stream>>>(xdbl, xp0, xp1, dtw, dtb, Alog, Dsk, Hin, ys);
    k_merge_ln<<<B_ * L_, 192, 0, stream>>>(ys, gw, gb, out);
}

// Round 8
// 332.933 us; speedup vs baseline: 8.8945x; 1.5566x over previous
//
#include <hip/hip_runtime.h>
#include <hip/hip_bf16.h>

#define B_  8
#define D_  192
#define H_  64
#define W_  64
#define L_  4096
#define K_  4
#define N_  16
#define R_  6
#define C_  38   // R + 2N
#define CP  40   // padded x_dbl row (floats)
#define CL_ 64   // scan chunk length
#define NC_ 64   // number of chunks (L_/CL_)

using bf16 = __hip_bfloat16;
typedef float v2f __attribute__((ext_vector_type(2)));

static __device__ __forceinline__ float softplus_f(float x) {
    return fmaxf(x, 0.f) + __logf(1.f + __expf(-fabsf(x)));
}
static __device__ __forceinline__ float bflo(unsigned u) {
    return __uint_as_float(u << 16);
}
static __device__ __forceinline__ float bfhi(unsigned u) {
    return __uint_as_float(u & 0xffff0000u);
}

// ---------------------------------------------------------------------------
// Kernel 1: transpose x (B,D,L) -> xp0b (B,L,D) row-major scan order and
// xp1b (B,L1,D) col-major order (l1 = w*H + h), bf16 (u is consumed bf16).
// ---------------------------------------------------------------------------
__global__ __launch_bounds__(256) void k_transpose(const float* __restrict__ x,
                                                   bf16* __restrict__ xp0b,
                                                   bf16* __restrict__ xp1b) {
    __shared__ float tile[32][33];
    int bi = blockIdx.x;
    int pg = bi & 127;          // L/32 tiles
    int dg = (bi >> 7) % 6;     // D/32 tiles
    int b  = bi / (128 * 6);
    int tx = threadIdx.x & 31;
    int ty = threadIdx.x >> 5;  // 0..7
    size_t xbase = (size_t)b * D_ * L_;
    #pragma unroll
    for (int i = 0; i < 4; i++) {
        int d = dg * 32 + ty + i * 8;
        tile[ty + i * 8][tx] = x[xbase + (size_t)d * L_ + pg * 32 + tx];
    }
    __syncthreads();
    #pragma unroll
    for (int i = 0; i < 4; i++) {
        int p = pg * 32 + ty + i * 8;
        float v = tile[tx][ty + i * 8];
        bf16 vb = __float2bfloat16(v);
        int d = dg * 32 + tx;
        xp0b[((size_t)b * L_ + p) * D_ + d] = vb;
        int hh = p >> 6, ww = p & 63;
        int r = ww * 64 + hh;   // l1 index
        xp1b[((size_t)b * L_ + r) * D_ + d] = vb;
    }
}

// ---------------------------------------------------------------------------
// Kernel 2: projection x_dbl[b,k,l,c] = sum_d xs[b,k,d,l] * W[k,c,d]
// Block = 64 positions x 38 channels. Wave = channel-quarter (wave-uniform,
// W loads scalarize to s_load); lane = position (x from LDS, b128 per group).
// ---------------------------------------------------------------------------
__global__ __launch_bounds__(256) void k_proj(const bf16* __restrict__ xp0b,
                                              const bf16* __restrict__ xp1b,
                                              const float* __restrict__ Wp,   // (K,38,192)
                                              float* __restrict__ xdbl) {     // (B,K,L,CP)
    __shared__ __align__(16) unsigned short xt[64 * 200]; // 25.6 KB, stride 200 bf16
    int blk  = blockIdx.x;
    int tile = blk & 63;            // L/64 tiles
    int bk   = blk >> 6;
    int k    = bk & 3;
    int b    = bk >> 2;
    const bf16* xpb = (k & 1) ? xp1b : xp0b;
    int g0 = (k < 2) ? tile * 64 : (L_ - 64 - tile * 64);

    const uint4* src = (const uint4*)(xpb + ((size_t)b * L_ + g0) * D_);
    for (int i = threadIdx.x; i < 1536; i += 256) {
        uint4 v = src[i];
        int row = i / 24, cg = i % 24;
        *((uint4*)(xt + row * 200 + cg * 8)) = v;
    }
    __syncthreads();

    int lane = threadIdx.x & 63;
    int wv   = __builtin_amdgcn_readfirstlane((int)(threadIdx.x >> 6)); // 0..3
    int c0   = wv * 10;
    int l    = tile * 64 + lane;
    int lrow = (k < 2) ? lane : (63 - lane);

    const unsigned short* xrow = xt + lrow * 200;

    float acc[10];
    #pragma unroll
    for (int ci = 0; ci < 10; ci++) acc[ci] = 0.f;

    for (int kk = 0; kk < 24; kk++) {       // 24 groups of 8 d-channels
        uint4 xv = *((const uint4*)(xrow + kk * 8));
        float xf0 = bflo(xv.x), xf1 = bfhi(xv.x);
        float xf2 = bflo(xv.y), xf3 = bfhi(xv.y);
        float xf4 = bflo(xv.z), xf5 = bfhi(xv.z);
        float xf6 = bflo(xv.w), xf7 = bfhi(xv.w);
        #pragma unroll
        for (int ci = 0; ci < 10; ci++) {
            int c = c0 + ci; if (c > 37) c = 37;     // wave 3: dup of c37 (harmless)
            const float* w = Wp + ((size_t)k * C_ + c) * D_ + kk * 8;  // uniform -> s_load
            float4 w0 = *((const float4*)w);
            float4 w1 = *((const float4*)(w + 4));
            acc[ci] = fmaf(xf0, w0.x, acc[ci]); acc[ci] = fmaf(xf1, w0.y, acc[ci]);
            acc[ci] = fmaf(xf2, w0.z, acc[ci]); acc[ci] = fmaf(xf3, w0.w, acc[ci]);
            acc[ci] = fmaf(xf4, w1.x, acc[ci]); acc[ci] = fmaf(xf5, w1.y, acc[ci]);
            acc[ci] = fmaf(xf6, w1.z, acc[ci]); acc[ci] = fmaf(xf7, w1.w, acc[ci]);
        }
    }
    float* orow = xdbl + ((size_t)bk * L_ + l) * CP;
    #pragma unroll
    for (int ci = 0; ci < 10; ci++) {
        int c = c0 + ci; if (c > 37) c = 37;
        orow[c] = acc[ci];
    }
}

// ---------------------------------------------------------------------------
// Kernel 3 (pass 1): per-chunk partial scan from h=0. Packed f32 math; xdbl
// rows via block-uniform s_load; u-tile staged in LDS as bf16 (kills the
// per-step global-load latency that capped round 5).
// ---------------------------------------------------------------------------
__global__ __launch_bounds__(192) void k_pass1(const float* __restrict__ xdbl,
                                               const bf16* __restrict__ xp0b,
                                               const bf16* __restrict__ xp1b,
                                               const float* __restrict__ dtw,   // (K,D,R)
                                               const float* __restrict__ dtb,   // (K,D)
                                               const float* __restrict__ Alog,  // (K*D,N)
                                               bf16* __restrict__ Pst,
                                               bf16* __restrict__ Hloc) {
    __shared__ __align__(16) unsigned short ut[CL_ * D_];  // 24.6 KB
    int blk = blockIdx.x;
    int c   = blk & (NC_ - 1);
    int bk  = blk >> 6;
    int k   = bk & 3;
    int b   = bk >> 2;
    int d   = threadIdx.x;

    int l0 = c * CL_;
    const bf16* xpb = (k & 1) ? xp1b : xp0b;
    int base_lu = (k < 2) ? l0 : (L_ - CL_ - l0);
    // stage u tile (coalesced): 1536 uint4 over 192 threads = 8 each
    {
        const uint4* usrc = (const uint4*)(xpb + ((size_t)b * L_ + base_lu) * D_);
        uint4* udst = (uint4*)ut;
        #pragma unroll
        for (int i = 0; i < 8; i++) udst[threadIdx.x + i * 192] = usrc[threadIdx.x + i * 192];
    }

    v2f A2[8];     // A * log2(e) pairs, for exp2
    #pragma unroll
    for (int i = 0; i < 8; i++) {
        A2[i].x = -__expf(Alog[((size_t)(k * D_ + d)) * N_ + 2*i])   * 1.44269504f;
        A2[i].y = -__expf(Alog[((size_t)(k * D_ + d)) * N_ + 2*i+1]) * 1.44269504f;
    }
    float wr[R_];
    #pragma unroll
    for (int r = 0; r < R_; r++) wr[r] = dtw[(k * D_ + d) * R_ + r];
    float bias = dtb[k * D_ + d];

    v2f h[8];
    #pragma unroll
    for (int i = 0; i < 8; i++) { h[i].x = 0.f; h[i].y = 0.f; }
    float S = 0.f;
    const float* rb = xdbl + ((size_t)bk * L_ + l0) * CP;

    int uidx  = ((k < 2) ? 0 : (CL_ - 1)) * D_ + d;
    int ustep = (k < 2) ? D_ : -D_;
    __syncthreads();

    #pragma unroll 2
    for (int s = 0; s < CL_; s++) {
        const float4* r4 = (const float4*)(rb + s * CP);   // block-uniform -> s_load
        float4 q0 = r4[0], q1 = r4[1], q2 = r4[2], q3 = r4[3], q4 = r4[4], q5 = r4[5];
        float dpre = bias + wr[0]*q0.x + wr[1]*q0.y + wr[2]*q0.z + wr[3]*q0.w
                          + wr[4]*q1.x + wr[5]*q1.y;
        float delta = softplus_f(dpre);
        float u = bflo(ut[uidx]);  uidx += ustep;          // ds_read_u16
        float du = delta * u;
        S += delta;
        v2f Bv[8] = {{q1.z,q1.w},{q2.x,q2.y},{q2.z,q2.w},{q3.x,q3.y},
                     {q3.z,q3.w},{q4.x,q4.y},{q4.z,q4.w},{q5.x,q5.y}};
        #pragma unroll
        for (int i = 0; i < 8; i++) {
            v2f t = A2[i] * delta;
            v2f dA;
            dA.x = __builtin_amdgcn_exp2f(t.x);
            dA.y = __builtin_amdgcn_exp2f(t.y);
            h[i] = dA * h[i] + Bv[i] * du;
        }
    }
    size_t o = ((size_t)blk * D_ + d) * N_;   // blk == bk*NC_ + c
    #pragma unroll
    for (int i = 0; i < 8; i++) {
        v2f t = A2[i] * S;
        Pst[o + 2*i]   = __float2bfloat16(__builtin_amdgcn_exp2f(t.x));
        Pst[o + 2*i+1] = __float2bfloat16(__builtin_amdgcn_exp2f(t.y));
        Hloc[o + 2*i]   = __float2bfloat16(h[i].x);
        Hloc[o + 2*i+1] = __float2bfloat16(h[i].y);
    }
}

// ---------------------------------------------------------------------------
// Kernel 4 (pass 2): chunk-prefix scan over NC_ chunks per (b,k,d,n).
// ---------------------------------------------------------------------------
__global__ __launch_bounds__(256) void k_pass2(const bf16* __restrict__ Pst,
                                               const bf16* __restrict__ Hloc,
                                               bf16* __restrict__ Hin) {
    int idx = blockIdx.x * 256 + threadIdx.x;   // over B*K*D*N
    int bk  = idx / (D_ * N_);
    int dn  = idx % (D_ * N_);
    float hh = 0.f;
    for (int c = 0; c < NC_; c++) {
        size_t o = ((size_t)bk * NC_ + c) * (D_ * N_) + dn;
        Hin[o] = __float2bfloat16(hh);
        hh = __bfloat162float(Pst[o]) * hh + __bfloat162float(Hloc[o]);
    }
}

// ---------------------------------------------------------------------------
// Kernel 5 (pass 3): recompute chunk scan with true h0, emit
// ys[b,k,l,d] = C_l . h_l + u * Ds (bf16). u-tile in LDS, xdbl via s_load.
// ---------------------------------------------------------------------------
__global__ __launch_bounds__(192) void k_pass3(const float* __restrict__ xdbl,
                                               const bf16* __restrict__ xp0b,
                                               const bf16* __restrict__ xp1b,
                                               const float* __restrict__ dtw,
                                               const float* __restrict__ dtb,
                                               const float* __restrict__ Alog,
                                               const float* __restrict__ Dsk,  // (K*D,)
                                               const bf16* __restrict__ Hin,
                                               bf16* __restrict__ ys) {        // (B,K,L,D)
    __shared__ __align__(16) unsigned short ut[CL_ * D_];  // 24.6 KB
    int blk = blockIdx.x;
    int c   = blk & (NC_ - 1);
    int bk  = blk >> 6;
    int k   = bk & 3;
    int b   = bk >> 2;
    int d   = threadIdx.x;

    int l0 = c * CL_;
    const bf16* xpb = (k & 1) ? xp1b : xp0b;
    int base_lu = (k < 2) ? l0 : (L_ - CL_ - l0);
    {
        const uint4* usrc = (const uint4*)(xpb + ((size_t)b * L_ + base_lu) * D_);
        uint4* udst = (uint4*)ut;
        #pragma unroll
        for (int i = 0; i < 8; i++) udst[threadIdx.x + i * 192] = usrc[threadIdx.x + i * 192];
    }

    v2f A2[8];
    #pragma unroll
    for (int i = 0; i < 8; i++) {
        A2[i].x = -__expf(Alog[((size_t)(k * D_ + d)) * N_ + 2*i])   * 1.44269504f;
        A2[i].y = -__expf(Alog[((size_t)(k * D_ + d)) * N_ + 2*i+1]) * 1.44269504f;
    }
    float wr[R_];
    #pragma unroll
    for (int r = 0; r < R_; r++) wr[r] = dtw[(k * D_ + d) * R_ + r];
    float bias = dtb[k * D_ + d];
    float DsV  = Dsk[k * D_ + d];

    v2f h[8];
    size_t o = ((size_t)blk * D_ + d) * N_;
    #pragma unroll
    for (int i = 0; i < 8; i++) {
        h[i].x = __bfloat162float(Hin[o + 2*i]);
        h[i].y = __bfloat162float(Hin[o + 2*i+1]);
    }

    const float* rb = xdbl + ((size_t)bk * L_ + l0) * CP;
    bf16* yp = ys + ((size_t)bk * L_ + l0) * D_ + d;
    int uidx  = ((k < 2) ? 0 : (CL_ - 1)) * D_ + d;
    int ustep = (k < 2) ? D_ : -D_;
    __syncthreads();

    #pragma unroll 2
    for (int s = 0; s < CL_; s++) {
        const float4* r4 = (const float4*)(rb + s * CP);   // block-uniform -> s_load
        float4 q0 = r4[0], q1 = r4[1], q2 = r4[2], q3 = r4[3], q4 = r4[4];
        float4 q5 = r4[5], q6 = r4[6], q7 = r4[7], q8 = r4[8], q9 = r4[9];
        float dpre = bias + wr[0]*q0.x + wr[1]*q0.y + wr[2]*q0.z + wr[3]*q0.w
                          + wr[4]*q1.x + wr[5]*q1.y;
        float delta = softplus_f(dpre);
        float u = bflo(ut[uidx]);  uidx += ustep;          // ds_read_u16
        float du = delta * u;
        v2f Bv[8] = {{q1.z,q1.w},{q2.x,q2.y},{q2.z,q2.w},{q3.x,q3.y},
                     {q3.z,q3.w},{q4.x,q4.y},{q4.z,q4.w},{q5.x,q5.y}};
        v2f Cv[8] = {{q5.z,q5.w},{q6.x,q6.y},{q6.z,q6.w},{q7.x,q7.y},
                     {q7.z,q7.w},{q8.x,q8.y},{q8.z,q8.w},{q9.x,q9.y}};
        v2f y2; y2.x = 0.f; y2.y = 0.f;
        #pragma unroll
        for (int i = 0; i < 8; i++) {
            v2f t = A2[i] * delta;
            v2f dA;
            dA.x = __builtin_amdgcn_exp2f(t.x);
            dA.y = __builtin_amdgcn_exp2f(t.y);
            h[i] = dA * h[i] + Bv[i] * du;
            y2   = y2 + h[i] * Cv[i];
        }
        float y = y2.x + y2.y;
        *yp = __float2bfloat16(y + u * DsV);
        yp += D_;
    }
}

// ---------------------------------------------------------------------------
// Kernel 6: cross-merge (4 directions) + LayerNorm over D, output (B,H,W,D)
// ---------------------------------------------------------------------------
__global__ __launch_bounds__(192) void k_merge_ln(const bf16* __restrict__ ys,
                                                  const float* __restrict__ gw,
                                                  const float* __restrict__ gb,
                                                  float* __restrict__ out) {
    int p = blockIdx.x & (L_ - 1);
    int b = blockIdx.x >> 12;     // L_ = 4096
    int d = threadIdx.x;
    int hh = p >> 6, ww = p & 63;
    int l1 = ww * 64 + hh;
    size_t base = (size_t)b * K_ * L_ * D_;
    float v = __bfloat162float(ys[base + ((size_t)0 * L_ + p) * D_ + d])
            + __bfloat162float(ys[base + ((size_t)2 * L_ + (L_ - 1 - p)) * D_ + d])
            + __bfloat162float(ys[base + ((size_t)1 * L_ + l1) * D_ + d])
            + __bfloat162float(ys[base + ((size_t)3 * L_ + (L_ - 1 - l1)) * D_ + d]);
    float s1 = v, s2 = v * v;
    #pragma unroll
    for (int off = 32; off; off >>= 1) {
        s1 += __shfl_down(s1, off);
        s2 += __shfl_down(s2, off);
    }
    __shared__ float aS[3], aQ[3];
    int wid = d >> 6, lane = d & 63;
    if (lane == 0) { aS[wid] = s1; aQ[wid] = s2; }
    __syncthreads();
    float ts1 = aS[0] + aS[1] + aS[2];
    float ts2 = aQ[0] + aQ[1] + aQ[2];
    float mean = ts1 * (1.f / 192.f);
    float var  = ts2 * (1.f / 192.f) - mean * mean;
    float inv  = rsqrtf(var + 1e-5f);
    out[((size_t)b * L_ + p) * D_ + d] = (v - mean) * inv * gw[d] + gb[d];
}

// ---------------------------------------------------------------------------
extern "C" void kernel_launch(void* const* d_in, const int* in_sizes, int n_in,
                              void* d_out, int out_size, void* d_ws, size_t ws_size,
                              hipStream_t stream) {
    const float* x    = (const float*)d_in[0];
    const float* Wp   = (const float*)d_in[1];
    const float* dtw  = (const float*)d_in[2];
    const float* dtb  = (const float*)d_in[3];
    const float* Alog = (const float*)d_in[4];
    const float* Dsk  = (const float*)d_in[5];
    const float* gw   = (const float*)d_in[6];
    const float* gb   = (const float*)d_in[7];
    float* out = (float*)d_out;

    char* ws = (char*)d_ws;
    const size_t S1b = (size_t)B_ * L_ * D_ * 2;            // 12.6 MB (xp0b/xp1b)
    const size_t Sx  = (size_t)B_ * K_ * L_ * CP * 4;       // 21.0 MB (xdbl)
    const size_t Ss  = (size_t)B_ * K_ * NC_ * D_ * N_ * 2; // 12.6 MB (P/Hloc/Hin)
    char* p = ws;
    bf16*  xp0b = (bf16*)p;   p += S1b;
    bf16*  xp1b = (bf16*)p;   p += S1b;
    float* xdbl = (float*)p;  p += Sx;
    bf16*  Pst  = (bf16*)p;   p += Ss;
    bf16*  Hloc = (bf16*)p;   p += Ss;
    bf16*  Hin  = (bf16*)p;   p += Ss;
    bf16*  ys   = (bf16*)p;   // 50.3 MB; total ~135 MB

    k_transpose<<<B_ * 6 * 128, 256, 0, stream>>>(x, xp0b, xp1b);
    k_proj<<<B_ * K_ * (L_ / 64), 256, 0, stream>>>(xp0b, xp1b, Wp, xdbl);
    k_pass1<<<B_ * K_ * NC_, 192, 0, stream>>>(xdbl, xp0b, xp1b, dtw, dtb, Alog, Pst, Hloc);
    k_pass2<<<(B_ * K_ * D_ * N_) / 256, 256, 0, stream>>>(Pst, Hloc, Hin);
    k_pass3<<<B_ * K_ * NC_, 192, 0, stream>>>(xdbl, xp0b, xp1b, dtw, dtb, Alog, Dsk, Hin, ys);
    k_merge_ln<<<B_ * L_, 192, 0, stream>>>(ys, gw, gb, out);
}

// Round 9
// 302.794 us; speedup vs baseline: 9.7799x; 1.0995x over previous
//
#include <hip/hip_runtime.h>
#include <hip/hip_bf16.h>

#define B_  8
#define D_  192
#define H_  64
#define W_  64
#define L_  4096
#define K_  4
#define N_  16
#define R_  6
#define C_  38   // R + 2N
#define CP  40   // padded x_dbl row (floats)
#define CL_ 64   // scan chunk length
#define NC_ 64   // number of chunks (L_/CL_)

using bf16 = __hip_bfloat16;
typedef float v2f __attribute__((ext_vector_type(2)));
typedef short v8s __attribute__((ext_vector_type(8)));   // 8 bf16 (4 VGPRs)
typedef float f32x4 __attribute__((ext_vector_type(4))); // MFMA acc

static __device__ __forceinline__ float softplus_f(float x) {
    return fmaxf(x, 0.f) + __logf(1.f + __expf(-fabsf(x)));
}
static __device__ __forceinline__ float bflo(unsigned u) {
    return __uint_as_float(u << 16);
}

// ---------------------------------------------------------------------------
// Kernel 1: transpose x (B,D,L) -> xp0b (B,L,D) row-major scan order and
// xp1b (B,L1,D) col-major order (l1 = w*H + h), bf16.
// ---------------------------------------------------------------------------
__global__ __launch_bounds__(256) void k_transpose(const float* __restrict__ x,
                                                   bf16* __restrict__ xp0b,
                                                   bf16* __restrict__ xp1b) {
    __shared__ float tile[32][33];
    int bi = blockIdx.x;
    int pg = bi & 127;          // L/32 tiles
    int dg = (bi >> 7) % 6;     // D/32 tiles
    int b  = bi / (128 * 6);
    int tx = threadIdx.x & 31;
    int ty = threadIdx.x >> 5;  // 0..7
    size_t xbase = (size_t)b * D_ * L_;
    #pragma unroll
    for (int i = 0; i < 4; i++) {
        int d = dg * 32 + ty + i * 8;
        tile[ty + i * 8][tx] = x[xbase + (size_t)d * L_ + pg * 32 + tx];
    }
    __syncthreads();
    #pragma unroll
    for (int i = 0; i < 4; i++) {
        int p = pg * 32 + ty + i * 8;
        float v = tile[tx][ty + i * 8];
        bf16 vb = __float2bfloat16(v);
        int d = dg * 32 + tx;
        xp0b[((size_t)b * L_ + p) * D_ + d] = vb;
        int hh = p >> 6, ww = p & 63;
        int r = ww * 64 + hh;   // l1 index
        xp1b[((size_t)b * L_ + r) * D_ + d] = vb;
    }
}

// ---------------------------------------------------------------------------
// Kernel 2 (MFMA): x_dbl[b,k,l,c] = sum_d xs[b,k,d,l] * W[k,c,d]
// GEMM M=64(pos)/block x N=48(ch,padded) x K=192, bf16 16x16x32 MFMA.
// x tile + W (bf16-converted) in LDS, stride 200 (2-way bank alias = free).
// A-frag: A[m=lane&15][k=(lane>>4)*8+j]; B-frag: B[k][n=lane&15];
// C/D: col=lane&15, row=(lane>>4)*4+reg  [per m89-verified mapping].
// ---------------------------------------------------------------------------
__global__ __launch_bounds__(256) void k_proj(const bf16* __restrict__ xp0b,
                                              const bf16* __restrict__ xp1b,
                                              const float* __restrict__ Wp,   // (K,38,192) f32
                                              float* __restrict__ xdbl) {     // (B,K,L,CP)
    __shared__ __align__(16) unsigned short xt[64 * 200]; // 25.6 KB (rows = scan order)
    __shared__ __align__(16) unsigned short wt[48 * 200]; // 19.2 KB
    int blk  = blockIdx.x;
    int tile = blk & 63;            // L/64 tiles
    int bk   = blk >> 6;
    int k    = bk & 3;
    int b    = bk >> 2;
    const bf16* xpb = (k & 1) ? xp1b : xp0b;
    int g0 = (k < 2) ? tile * 64 : (L_ - 64 - tile * 64);

    // zero-pad W rows 38..47 (uint granularity: rows*100 uints)
    unsigned* wtu = (unsigned*)wt;
    for (int i = threadIdx.x; i < 1000; i += 256) wtu[3800 + i] = 0u;
    // convert W (38x192 f32) -> bf16, row stride 200
    const float2* wsrc = (const float2*)(Wp + (size_t)k * C_ * D_);
    for (int i = threadIdx.x; i < 3648; i += 256) {   // 38*96 float2
        float2 wv2 = wsrc[i];
        int c = i / 96, dp = i % 96;
        bf16 b0 = __float2bfloat16(wv2.x), b1 = __float2bfloat16(wv2.y);
        unsigned pack = ((unsigned)(*(unsigned short*)&b1) << 16) |
                        (unsigned)(*(unsigned short*)&b0);
        wtu[c * 100 + dp] = pack;
    }
    // stage x tile (64 rows x 192 bf16), reversing rows for k>=2
    const uint4* src = (const uint4*)(xpb + ((size_t)b * L_ + g0) * D_);
    for (int i = threadIdx.x; i < 1536; i += 256) {
        uint4 v = src[i];
        int row = i / 24, cg = i % 24;
        int rr = (k < 2) ? row : 63 - row;
        *((uint4*)(xt + rr * 200 + cg * 8)) = v;
    }
    __syncthreads();

    int wv   = threadIdx.x >> 6;   // 0..3 -> M-tile
    int lane = threadIdx.x & 63;
    int m0   = wv * 16;
    int mrow = lane & 15;
    int kq   = lane >> 4;          // 0..3

    f32x4 acc[3];
    #pragma unroll
    for (int nt = 0; nt < 3; nt++) acc[nt] = (f32x4){0.f, 0.f, 0.f, 0.f};

    const unsigned short* arow = xt + (m0 + mrow) * 200 + kq * 8;
    const unsigned short* brow = wt + mrow * 200 + kq * 8;
    #pragma unroll
    for (int kt = 0; kt < 6; kt++) {
        v8s af = *(const v8s*)(arow + kt * 32);
        #pragma unroll
        for (int nt = 0; nt < 3; nt++) {
            v8s bf = *(const v8s*)(brow + nt * 16 * 200 + kt * 32);
            acc[nt] = __builtin_amdgcn_mfma_f32_16x16x32_bf16(af, bf, acc[nt], 0, 0, 0);
        }
    }

    int l0g = tile * 64;
    #pragma unroll
    for (int nt = 0; nt < 3; nt++) {
        int c = nt * 16 + mrow;        // col = lane&15
        if (c < C_) {
            #pragma unroll
            for (int r = 0; r < 4; r++) {
                int m = m0 + kq * 4 + r;   // row = (lane>>4)*4 + reg
                xdbl[((size_t)bk * L_ + l0g + m) * CP + c] = acc[nt][r];
            }
        }
    }
}

// ---------------------------------------------------------------------------
// Kernel 3 (pass 1): per-chunk partial scan from h=0. Packed f32 math; xdbl
// rows via block-uniform s_load; u-tile staged in LDS as bf16.
// ---------------------------------------------------------------------------
__global__ __launch_bounds__(192) void k_pass1(const float* __restrict__ xdbl,
                                               const bf16* __restrict__ xp0b,
                                               const bf16* __restrict__ xp1b,
                                               const float* __restrict__ dtw,   // (K,D,R)
                                               const float* __restrict__ dtb,   // (K,D)
                                               const float* __restrict__ Alog,  // (K*D,N)
                                               bf16* __restrict__ Pst,
                                               bf16* __restrict__ Hloc) {
    __shared__ __align__(16) unsigned short ut[CL_ * D_];  // 24.6 KB
    int blk = blockIdx.x;
    int c   = blk & (NC_ - 1);
    int bk  = blk >> 6;
    int k   = bk & 3;
    int b   = bk >> 2;
    int d   = threadIdx.x;

    int l0 = c * CL_;
    const bf16* xpb = (k & 1) ? xp1b : xp0b;
    int base_lu = (k < 2) ? l0 : (L_ - CL_ - l0);
    {
        const uint4* usrc = (const uint4*)(xpb + ((size_t)b * L_ + base_lu) * D_);
        uint4* udst = (uint4*)ut;
        #pragma unroll
        for (int i = 0; i < 8; i++) udst[threadIdx.x + i * 192] = usrc[threadIdx.x + i * 192];
    }

    v2f A2[8];     // A * log2(e) pairs, for exp2
    #pragma unroll
    for (int i = 0; i < 8; i++) {
        A2[i].x = -__expf(Alog[((size_t)(k * D_ + d)) * N_ + 2*i])   * 1.44269504f;
        A2[i].y = -__expf(Alog[((size_t)(k * D_ + d)) * N_ + 2*i+1]) * 1.44269504f;
    }
    float wr[R_];
    #pragma unroll
    for (int r = 0; r < R_; r++) wr[r] = dtw[(k * D_ + d) * R_ + r];
    float bias = dtb[k * D_ + d];

    v2f h[8];
    #pragma unroll
    for (int i = 0; i < 8; i++) { h[i].x = 0.f; h[i].y = 0.f; }
    float S = 0.f;
    const float* rb = xdbl + ((size_t)bk * L_ + l0) * CP;

    int uidx  = ((k < 2) ? 0 : (CL_ - 1)) * D_ + d;
    int ustep = (k < 2) ? D_ : -D_;
    __syncthreads();

    #pragma unroll 2
    for (int s = 0; s < CL_; s++) {
        const float4* r4 = (const float4*)(rb + s * CP);   // block-uniform -> s_load
        float4 q0 = r4[0], q1 = r4[1], q2 = r4[2], q3 = r4[3], q4 = r4[4], q5 = r4[5];
        float dpre = bias + wr[0]*q0.x + wr[1]*q0.y + wr[2]*q0.z + wr[3]*q0.w
                          + wr[4]*q1.x + wr[5]*q1.y;
        float delta = softplus_f(dpre);
        float u = bflo(ut[uidx]);  uidx += ustep;          // ds_read_u16
        float du = delta * u;
        S += delta;
        v2f Bv[8] = {{q1.z,q1.w},{q2.x,q2.y},{q2.z,q2.w},{q3.x,q3.y},
                     {q3.z,q3.w},{q4.x,q4.y},{q4.z,q4.w},{q5.x,q5.y}};
        #pragma unroll
        for (int i = 0; i < 8; i++) {
            v2f t = A2[i] * delta;
            v2f dA;
            dA.x = __builtin_amdgcn_exp2f(t.x);
            dA.y = __builtin_amdgcn_exp2f(t.y);
            h[i] = dA * h[i] + Bv[i] * du;
        }
    }
    size_t o = ((size_t)blk * D_ + d) * N_;   // blk == bk*NC_ + c
    #pragma unroll
    for (int i = 0; i < 8; i++) {
        v2f t = A2[i] * S;
        Pst[o + 2*i]   = __float2bfloat16(__builtin_amdgcn_exp2f(t.x));
        Pst[o + 2*i+1] = __float2bfloat16(__builtin_amdgcn_exp2f(t.y));
        Hloc[o + 2*i]   = __float2bfloat16(h[i].x);
        Hloc[o + 2*i+1] = __float2bfloat16(h[i].y);
    }
}

// ---------------------------------------------------------------------------
// Kernel 4 (pass 2): chunk-prefix scan over NC_ chunks per (b,k,d,n).
// ---------------------------------------------------------------------------
__global__ __launch_bounds__(256) void k_pass2(const bf16* __restrict__ Pst,
                                               const bf16* __restrict__ Hloc,
                                               bf16* __restrict__ Hin) {
    int idx = blockIdx.x * 256 + threadIdx.x;   // over B*K*D*N
    int bk  = idx / (D_ * N_);
    int dn  = idx % (D_ * N_);
    float hh = 0.f;
    for (int c = 0; c < NC_; c++) {
        size_t o = ((size_t)bk * NC_ + c) * (D_ * N_) + dn;
        Hin[o] = __float2bfloat16(hh);
        hh = __bfloat162float(Pst[o]) * hh + __bfloat162float(Hloc[o]);
    }
}

// ---------------------------------------------------------------------------
// Kernel 5 (pass 3): recompute chunk scan with true h0, emit
// ys[b,k,l,d] = C_l . h_l + u * Ds (bf16). u-tile in LDS, xdbl via s_load.
// ---------------------------------------------------------------------------
__global__ __launch_bounds__(192) void k_pass3(const float* __restrict__ xdbl,
                                               const bf16* __restrict__ xp0b,
                                               const bf16* __restrict__ xp1b,
                                               const float* __restrict__ dtw,
                                               const float* __restrict__ dtb,
                                               const float* __restrict__ Alog,
                                               const float* __restrict__ Dsk,  // (K*D,)
                                               const bf16* __restrict__ Hin,
                                               bf16* __restrict__ ys) {        // (B,K,L,D)
    __shared__ __align__(16) unsigned short ut[CL_ * D_];  // 24.6 KB
    int blk = blockIdx.x;
    int c   = blk & (NC_ - 1);
    int bk  = blk >> 6;
    int k   = bk & 3;
    int b   = bk >> 2;
    int d   = threadIdx.x;

    int l0 = c * CL_;
    const bf16* xpb = (k & 1) ? xp1b : xp0b;
    int base_lu = (k < 2) ? l0 : (L_ - CL_ - l0);
    {
        const uint4* usrc = (const uint4*)(xpb + ((size_t)b * L_ + base_lu) * D_);
        uint4* udst = (uint4*)ut;
        #pragma unroll
        for (int i = 0; i < 8; i++) udst[threadIdx.x + i * 192] = usrc[threadIdx.x + i * 192];
    }

    v2f A2[8];
    #pragma unroll
    for (int i = 0; i < 8; i++) {
        A2[i].x = -__expf(Alog[((size_t)(k * D_ + d)) * N_ + 2*i])   * 1.44269504f;
        A2[i].y = -__expf(Alog[((size_t)(k * D_ + d)) * N_ + 2*i+1]) * 1.44269504f;
    }
    float wr[R_];
    #pragma unroll
    for (int r = 0; r < R_; r++) wr[r] = dtw[(k * D_ + d) * R_ + r];
    float bias = dtb[k * D_ + d];
    float DsV  = Dsk[k * D_ + d];

    v2f h[8];
    size_t o = ((size_t)blk * D_ + d) * N_;
    #pragma unroll
    for (int i = 0; i < 8; i++) {
        h[i].x = __bfloat162float(Hin[o + 2*i]);
        h[i].y = __bfloat162float(Hin[o + 2*i+1]);
    }

    const float* rb = xdbl + ((size_t)bk * L_ + l0) * CP;
    bf16* yp = ys + ((size_t)bk * L_ + l0) * D_ + d;
    int uidx  = ((k < 2) ? 0 : (CL_ - 1)) * D_ + d;
    int ustep = (k < 2) ? D_ : -D_;
    __syncthreads();

    #pragma unroll 2
    for (int s = 0; s < CL_; s++) {
        const float4* r4 = (const float4*)(rb + s * CP);   // block-uniform -> s_load
        float4 q0 = r4[0], q1 = r4[1], q2 = r4[2], q3 = r4[3], q4 = r4[4];
        float4 q5 = r4[5], q6 = r4[6], q7 = r4[7], q8 = r4[8], q9 = r4[9];
        float dpre = bias + wr[0]*q0.x + wr[1]*q0.y + wr[2]*q0.z + wr[3]*q0.w
                          + wr[4]*q1.x + wr[5]*q1.y;
        float delta = softplus_f(dpre);
        float u = bflo(ut[uidx]);  uidx += ustep;          // ds_read_u16
        float du = delta * u;
        v2f Bv[8] = {{q1.z,q1.w},{q2.x,q2.y},{q2.z,q2.w},{q3.x,q3.y},
                     {q3.z,q3.w},{q4.x,q4.y},{q4.z,q4.w},{q5.x,q5.y}};
        v2f Cv[8] = {{q5.z,q5.w},{q6.x,q6.y},{q6.z,q6.w},{q7.x,q7.y},
                     {q7.z,q7.w},{q8.x,q8.y},{q8.z,q8.w},{q9.x,q9.y}};
        v2f y2; y2.x = 0.f; y2.y = 0.f;
        #pragma unroll
        for (int i = 0; i < 8; i++) {
            v2f t = A2[i] * delta;
            v2f dA;
            dA.x = __builtin_amdgcn_exp2f(t.x);
            dA.y = __builtin_amdgcn_exp2f(t.y);
            h[i] = dA * h[i] + Bv[i] * du;
            y2   = y2 + h[i] * Cv[i];
        }
        float y = y2.x + y2.y;
        *yp = __float2bfloat16(y + u * DsV);
        yp += D_;
    }
}

// ---------------------------------------------------------------------------
// Kernel 6: cross-merge (4 directions) + LayerNorm over D, output (B,H,W,D)
// ---------------------------------------------------------------------------
__global__ __launch_bounds__(192) void k_merge_ln(const bf16* __restrict__ ys,
                                                  const float* __restrict__ gw,
                                                  const float* __restrict__ gb,
                                                  float* __restrict__ out) {
    int p = blockIdx.x & (L_ - 1);
    int b = blockIdx.x >> 12;     // L_ = 4096
    int d = threadIdx.x;
    int hh = p >> 6, ww = p & 63;
    int l1 = ww * 64 + hh;
    size_t base = (size_t)b * K_ * L_ * D_;
    float v = __bfloat162float(ys[base + ((size_t)0 * L_ + p) * D_ + d])
            + __bfloat162float(ys[base + ((size_t)2 * L_ + (L_ - 1 - p)) * D_ + d])
            + __bfloat162float(ys[base + ((size_t)1 * L_ + l1) * D_ + d])
            + __bfloat162float(ys[base + ((size_t)3 * L_ + (L_ - 1 - l1)) * D_ + d]);
    float s1 = v, s2 = v * v;
    #pragma unroll
    for (int off = 32; off; off >>= 1) {
        s1 += __shfl_down(s1, off);
        s2 += __shfl_down(s2, off);
    }
    __shared__ float aS[3], aQ[3];
    int wid = d >> 6, lane = d & 63;
    if (lane == 0) { aS[wid] = s1; aQ[wid] = s2; }
    __syncthreads();
    float ts1 = aS[0] + aS[1] + aS[2];
    float ts2 = aQ[0] + aQ[1] + aQ[2];
    float mean = ts1 * (1.f / 192.f);
    float var  = ts2 * (1.f / 192.f) - mean * mean;
    float inv  = rsqrtf(var + 1e-5f);
    out[((size_t)b * L_ + p) * D_ + d] = (v - mean) * inv * gw[d] + gb[d];
}

// ---------------------------------------------------------------------------
extern "C" void kernel_launch(void* const* d_in, const int* in_sizes, int n_in,
                              void* d_out, int out_size, void* d_ws, size_t ws_size,
                              hipStream_t stream) {
    const float* x    = (const float*)d_in[0];
    const float* Wp   = (const float*)d_in[1];
    const float* dtw  = (const float*)d_in[2];
    const float* dtb  = (const float*)d_in[3];
    const float* Alog = (const float*)d_in[4];
    const float* Dsk  = (const float*)d_in[5];
    const float* gw   = (const float*)d_in[6];
    const float* gb   = (const float*)d_in[7];
    float* out = (float*)d_out;

    char* ws = (char*)d_ws;
    const size_t S1b = (size_t)B_ * L_ * D_ * 2;            // 12.6 MB (xp0b/xp1b)
    const size_t Sx  = (size_t)B_ * K_ * L_ * CP * 4;       // 21.0 MB (xdbl)
    const size_t Ss  = (size_t)B_ * K_ * NC_ * D_ * N_ * 2; // 12.6 MB (P/Hloc/Hin)
    char* p = ws;
    bf16*  xp0b = (bf16*)p;   p += S1b;
    bf16*  xp1b = (bf16*)p;   p += S1b;
    float* xdbl = (float*)p;  p += Sx;
    bf16*  Pst  = (bf16*)p;   p += Ss;
    bf16*  Hloc = (bf16*)p;   p += Ss;
    bf16*  Hin  = (bf16*)p;   p += Ss;
    bf16*  ys   = (bf16*)p;   // 50.3 MB; total ~135 MB

    k_transpose<<<B_ * 6 * 128, 256, 0, stream>>>(x, xp0b, xp1b);
    k_proj<<<B_ * K_ * (L_ / 64), 256, 0, stream>>>(xp0b, xp1b, Wp, xdbl);
    k_pass1<<<B_ * K_ * NC_, 192, 0, stream>>>(xdbl, xp0b, xp1b, dtw, dtb, Alog, Pst, Hloc);
    k_pass2<<<(B_ * K_ * D_ * N_) / 256, 256, 0, stream>>>(Pst, Hloc, Hin);
    k_pass3<<<B_ * K_ * NC_, 192, 0, stream>>>(xdbl, xp0b, xp1b, dtw, dtb, Alog, Dsk, Hin, ys);
    k_merge_ln<<<B_ * L_, 192, 0, stream>>>(ys, gw, gb, out);
}

// Round 10
// 265.210 us; speedup vs baseline: 11.1658x; 1.1417x over previous
//
#include <hip/hip_runtime.h>
#include <hip/hip_bf16.h>

#define B_  8
#define D_  192
#define H_  64
#define W_  64
#define L_  4096
#define K_  4
#define N_  16
#define R_  6
#define C_  38   // R + 2N
#define CP  40   // padded x_dbl row (floats)
#define CL_ 64   // scan chunk length
#define NC_ 64   // number of chunks (L_/CL_)

using bf16 = __hip_bfloat16;
typedef float v2f __attribute__((ext_vector_type(2)));
typedef short v8s __attribute__((ext_vector_type(8)));   // 8 bf16 (4 VGPRs)
typedef float f32x4 __attribute__((ext_vector_type(4))); // MFMA acc

static __device__ __forceinline__ float softplus_f(float x) {
    return fmaxf(x, 0.f) + __logf(1.f + __expf(-fabsf(x)));
}
static __device__ __forceinline__ float bflo(unsigned u) {
    return __uint_as_float(u << 16);
}

// ---------------------------------------------------------------------------
// Kernel 1: transpose x (B,D,L) -> xp0b (B,L,D) row-major scan order and
// xp1b (B,L1,D) col-major order (l1 = w*H + h), bf16.
// ---------------------------------------------------------------------------
__global__ __launch_bounds__(256) void k_transpose(const float* __restrict__ x,
                                                   bf16* __restrict__ xp0b,
                                                   bf16* __restrict__ xp1b) {
    __shared__ float tile[32][33];
    int bi = blockIdx.x;
    int pg = bi & 127;          // L/32 tiles
    int dg = (bi >> 7) % 6;     // D/32 tiles
    int b  = bi / (128 * 6);
    int tx = threadIdx.x & 31;
    int ty = threadIdx.x >> 5;  // 0..7
    size_t xbase = (size_t)b * D_ * L_;
    #pragma unroll
    for (int i = 0; i < 4; i++) {
        int d = dg * 32 + ty + i * 8;
        tile[ty + i * 8][tx] = x[xbase + (size_t)d * L_ + pg * 32 + tx];
    }
    __syncthreads();
    #pragma unroll
    for (int i = 0; i < 4; i++) {
        int p = pg * 32 + ty + i * 8;
        float v = tile[tx][ty + i * 8];
        bf16 vb = __float2bfloat16(v);
        int d = dg * 32 + tx;
        xp0b[((size_t)b * L_ + p) * D_ + d] = vb;
        int hh = p >> 6, ww = p & 63;
        int r = ww * 64 + hh;   // l1 index
        xp1b[((size_t)b * L_ + r) * D_ + d] = vb;
    }
}

// ---------------------------------------------------------------------------
// Kernel 2 (MFMA): x_dbl[b,k,l,c] = sum_d xs[b,k,d,l] * W[k,c,d]
// ---------------------------------------------------------------------------
__global__ __launch_bounds__(256) void k_proj(const bf16* __restrict__ xp0b,
                                              const bf16* __restrict__ xp1b,
                                              const float* __restrict__ Wp,   // (K,38,192) f32
                                              float* __restrict__ xdbl) {     // (B,K,L,CP)
    __shared__ __align__(16) unsigned short xt[64 * 200];
    __shared__ __align__(16) unsigned short wt[48 * 200];
    int blk  = blockIdx.x;
    int tile = blk & 63;
    int bk   = blk >> 6;
    int k    = bk & 3;
    int b    = bk >> 2;
    const bf16* xpb = (k & 1) ? xp1b : xp0b;
    int g0 = (k < 2) ? tile * 64 : (L_ - 64 - tile * 64);

    unsigned* wtu = (unsigned*)wt;
    for (int i = threadIdx.x; i < 1000; i += 256) wtu[3800 + i] = 0u;
    const float2* wsrc = (const float2*)(Wp + (size_t)k * C_ * D_);
    for (int i = threadIdx.x; i < 3648; i += 256) {   // 38*96 float2
        float2 wv2 = wsrc[i];
        int c = i / 96, dp = i % 96;
        bf16 b0 = __float2bfloat16(wv2.x), b1 = __float2bfloat16(wv2.y);
        unsigned pack = ((unsigned)(*(unsigned short*)&b1) << 16) |
                        (unsigned)(*(unsigned short*)&b0);
        wtu[c * 100 + dp] = pack;
    }
    const uint4* src = (const uint4*)(xpb + ((size_t)b * L_ + g0) * D_);
    for (int i = threadIdx.x; i < 1536; i += 256) {
        uint4 v = src[i];
        int row = i / 24, cg = i % 24;
        int rr = (k < 2) ? row : 63 - row;
        *((uint4*)(xt + rr * 200 + cg * 8)) = v;
    }
    __syncthreads();

    int wv   = threadIdx.x >> 6;
    int lane = threadIdx.x & 63;
    int m0   = wv * 16;
    int mrow = lane & 15;
    int kq   = lane >> 4;

    f32x4 acc[3];
    #pragma unroll
    for (int nt = 0; nt < 3; nt++) acc[nt] = (f32x4){0.f, 0.f, 0.f, 0.f};

    const unsigned short* arow = xt + (m0 + mrow) * 200 + kq * 8;
    const unsigned short* brow = wt + mrow * 200 + kq * 8;
    #pragma unroll
    for (int kt = 0; kt < 6; kt++) {
        v8s af = *(const v8s*)(arow + kt * 32);
        #pragma unroll
        for (int nt = 0; nt < 3; nt++) {
            v8s bf = *(const v8s*)(brow + nt * 16 * 200 + kt * 32);
            acc[nt] = __builtin_amdgcn_mfma_f32_16x16x32_bf16(af, bf, acc[nt], 0, 0, 0);
        }
    }

    int l0g = tile * 64;
    #pragma unroll
    for (int nt = 0; nt < 3; nt++) {
        int c = nt * 16 + mrow;
        if (c < C_) {
            #pragma unroll
            for (int r = 0; r < 4; r++) {
                int m = m0 + kq * 4 + r;
                xdbl[((size_t)bk * L_ + l0g + m) * CP + c] = acc[nt][r];
            }
        }
    }
}

// ---------------------------------------------------------------------------
// Kernel 3 (scanA): ONE scan pass from h=0 per chunk. Emits
// y_local = C.h_local + Ds*u (bf16), stores S_l (f32, inclusive delta-cumsum),
// and chunk summary P=exp(A*S_64), Hloc for the prefix pass. The h0
// contribution is added later by k_corr (decay-truncated).
// ---------------------------------------------------------------------------
__global__ __launch_bounds__(192) void k_scanA(const float* __restrict__ xdbl,
                                               const bf16* __restrict__ xp0b,
                                               const bf16* __restrict__ xp1b,
                                               const float* __restrict__ dtw,   // (K,D,R)
                                               const float* __restrict__ dtb,   // (K,D)
                                               const float* __restrict__ Alog,  // (K*D,N)
                                               const float* __restrict__ Dsk,   // (K*D,)
                                               bf16* __restrict__ Pst,
                                               bf16* __restrict__ Hloc,
                                               float* __restrict__ Sbuf,        // (B,K,L,D) f32
                                               bf16* __restrict__ ys) {         // (B,K,L,D)
    __shared__ __align__(16) unsigned short ut[CL_ * D_];  // 24.6 KB
    int blk = blockIdx.x;
    int c   = blk & (NC_ - 1);
    int bk  = blk >> 6;
    int k   = bk & 3;
    int b   = bk >> 2;
    int d   = threadIdx.x;

    int l0 = c * CL_;
    const bf16* xpb = (k & 1) ? xp1b : xp0b;
    int base_lu = (k < 2) ? l0 : (L_ - CL_ - l0);
    {
        const uint4* usrc = (const uint4*)(xpb + ((size_t)b * L_ + base_lu) * D_);
        uint4* udst = (uint4*)ut;
        #pragma unroll
        for (int i = 0; i < 8; i++) udst[threadIdx.x + i * 192] = usrc[threadIdx.x + i * 192];
    }

    v2f A2[8];     // A * log2(e) pairs, for exp2
    #pragma unroll
    for (int i = 0; i < 8; i++) {
        A2[i].x = -__expf(Alog[((size_t)(k * D_ + d)) * N_ + 2*i])   * 1.44269504f;
        A2[i].y = -__expf(Alog[((size_t)(k * D_ + d)) * N_ + 2*i+1]) * 1.44269504f;
    }
    float wr[R_];
    #pragma unroll
    for (int r = 0; r < R_; r++) wr[r] = dtw[(k * D_ + d) * R_ + r];
    float bias = dtb[k * D_ + d];
    float DsV  = Dsk[k * D_ + d];

    v2f h[8];
    #pragma unroll
    for (int i = 0; i < 8; i++) { h[i].x = 0.f; h[i].y = 0.f; }
    float S = 0.f;
    const float* rb = xdbl + ((size_t)bk * L_ + l0) * CP;
    float* Sp = Sbuf + ((size_t)bk * L_ + l0) * D_ + d;
    bf16* yp  = ys   + ((size_t)bk * L_ + l0) * D_ + d;

    int uidx  = ((k < 2) ? 0 : (CL_ - 1)) * D_ + d;
    int ustep = (k < 2) ? D_ : -D_;
    __syncthreads();

    #pragma unroll 2
    for (int s = 0; s < CL_; s++) {
        const float4* r4 = (const float4*)(rb + s * CP);   // block-uniform -> s_load
        float4 q0 = r4[0], q1 = r4[1], q2 = r4[2], q3 = r4[3], q4 = r4[4];
        float4 q5 = r4[5], q6 = r4[6], q7 = r4[7], q8 = r4[8], q9 = r4[9];
        float dpre = bias + wr[0]*q0.x + wr[1]*q0.y + wr[2]*q0.z + wr[3]*q0.w
                          + wr[4]*q1.x + wr[5]*q1.y;
        float delta = softplus_f(dpre);
        float u = bflo(ut[uidx]);  uidx += ustep;          // ds_read_u16
        float du = delta * u;
        S += delta;
        *Sp = S;  Sp += D_;
        v2f Bv[8] = {{q1.z,q1.w},{q2.x,q2.y},{q2.z,q2.w},{q3.x,q3.y},
                     {q3.z,q3.w},{q4.x,q4.y},{q4.z,q4.w},{q5.x,q5.y}};
        v2f Cv[8] = {{q5.z,q5.w},{q6.x,q6.y},{q6.z,q6.w},{q7.x,q7.y},
                     {q7.z,q7.w},{q8.x,q8.y},{q8.z,q8.w},{q9.x,q9.y}};
        v2f y2; y2.x = 0.f; y2.y = 0.f;
        #pragma unroll
        for (int i = 0; i < 8; i++) {
            v2f t = A2[i] * delta;
            v2f dA;
            dA.x = __builtin_amdgcn_exp2f(t.x);
            dA.y = __builtin_amdgcn_exp2f(t.y);
            h[i] = dA * h[i] + Bv[i] * du;
            y2   = y2 + h[i] * Cv[i];
        }
        float y = y2.x + y2.y;
        *yp = __float2bfloat16(y + u * DsV);
        yp += D_;
    }
    size_t o = ((size_t)blk * D_ + d) * N_;   // blk == bk*NC_ + c
    #pragma unroll
    for (int i = 0; i < 8; i++) {
        v2f t = A2[i] * S;
        Pst[o + 2*i]   = __float2bfloat16(__builtin_amdgcn_exp2f(t.x));
        Pst[o + 2*i+1] = __float2bfloat16(__builtin_amdgcn_exp2f(t.y));
        Hloc[o + 2*i]   = __float2bfloat16(h[i].x);
        Hloc[o + 2*i+1] = __float2bfloat16(h[i].y);
    }
}

// ---------------------------------------------------------------------------
// Kernel 4 (pass 2): chunk-prefix scan over NC_ chunks per (b,k,d,n).
// ---------------------------------------------------------------------------
__global__ __launch_bounds__(256) void k_pass2(const bf16* __restrict__ Pst,
                                               const bf16* __restrict__ Hloc,
                                               bf16* __restrict__ Hin) {
    int idx = blockIdx.x * 256 + threadIdx.x;   // over B*K*D*N
    int bk  = idx / (D_ * N_);
    int dn  = idx % (D_ * N_);
    float hh = 0.f;
    for (int c = 0; c < NC_; c++) {
        size_t o = ((size_t)bk * NC_ + c) * (D_ * N_) + dn;
        Hin[o] = __float2bfloat16(hh);
        hh = __bfloat162float(Pst[o]) * hh + __bfloat162float(Hloc[o]);
    }
}

// ---------------------------------------------------------------------------
// Kernel 5 (corr): ys += C_l . (exp(A*S_l) * h_in).  Fully parallel; the
// decay term dies after S_l*|A|min > 18*ln2, so a per-wave ballot exits the
// chunk tail early (typically ~16-25 of 64 steps alive).
// ---------------------------------------------------------------------------
__global__ __launch_bounds__(192) void k_corr(const float* __restrict__ xdbl,
                                              const float* __restrict__ Sbuf,
                                              const float* __restrict__ Alog,
                                              const bf16* __restrict__ Hin,
                                              bf16* __restrict__ ys) {
    int blk = blockIdx.x;
    int c   = blk & (NC_ - 1);
    if (c == 0) return;                        // h_in == 0 for first chunk
    int bk  = blk >> 6;
    int k   = bk & 3;
    int d   = threadIdx.x;

    float A2[N_];
    float aMax = -1e30f;
    #pragma unroll
    for (int n = 0; n < N_; n++) {
        A2[n] = -__expf(Alog[((size_t)(k * D_ + d)) * N_ + n]) * 1.44269504f;
        aMax = fmaxf(aMax, A2[n]);
    }
    float g[N_];
    size_t o = ((size_t)blk * D_ + d) * N_;
    #pragma unroll
    for (int n = 0; n < N_; n++) g[n] = __bfloat162float(Hin[o + n]);

    int l0 = c * CL_;
    const float* rb = xdbl + ((size_t)bk * L_ + l0) * CP;   // block-uniform
    const float* Sp = Sbuf + ((size_t)bk * L_ + l0) * D_ + d;
    bf16* yp = ys + ((size_t)bk * L_ + l0) * D_ + d;

    for (int s = 0; s < CL_; s++) {
        float S = *Sp;  Sp += D_;
        bool alive = (aMax * S > -18.f);       // 2^-18 ~ 4e-6: below bf16 noise
        if (__ballot(alive) == 0ull) break;
        const float4* r4 = (const float4*)(rb + s * CP + 20);  // C part: floats 20..39
        float4 c5 = r4[0], c6 = r4[1], c7 = r4[2], c8 = r4[3], c9 = r4[4];
        float Cv[N_] = {c5.z,c5.w,c6.x,c6.y,c6.z,c6.w,c7.x,c7.y,
                        c7.z,c7.w,c8.x,c8.y,c8.z,c8.w,c9.x,c9.y};
        float acc = 0.f;
        #pragma unroll
        for (int n = 0; n < N_; n++) {
            float e = __builtin_amdgcn_exp2f(A2[n] * S);
            acc = fmaf(Cv[n], e * g[n], acc);
        }
        float y = __bfloat162float(*yp) + acc;
        *yp = __float2bfloat16(y);
        yp += D_;
    }
}

// ---------------------------------------------------------------------------
// Kernel 6: cross-merge (4 directions) + LayerNorm over D, output (B,H,W,D)
// ---------------------------------------------------------------------------
__global__ __launch_bounds__(192) void k_merge_ln(const bf16* __restrict__ ys,
                                                  const float* __restrict__ gw,
                                                  const float* __restrict__ gb,
                                                  float* __restrict__ out) {
    int p = blockIdx.x & (L_ - 1);
    int b = blockIdx.x >> 12;     // L_ = 4096
    int d = threadIdx.x;
    int hh = p >> 6, ww = p & 63;
    int l1 = ww * 64 + hh;
    size_t base = (size_t)b * K_ * L_ * D_;
    float v = __bfloat162float(ys[base + ((size_t)0 * L_ + p) * D_ + d])
            + __bfloat162float(ys[base + ((size_t)2 * L_ + (L_ - 1 - p)) * D_ + d])
            + __bfloat162float(ys[base + ((size_t)1 * L_ + l1) * D_ + d])
            + __bfloat162float(ys[base + ((size_t)3 * L_ + (L_ - 1 - l1)) * D_ + d]);
    float s1 = v, s2 = v * v;
    #pragma unroll
    for (int off = 32; off; off >>= 1) {
        s1 += __shfl_down(s1, off);
        s2 += __shfl_down(s2, off);
    }
    __shared__ float aS[3], aQ[3];
    int wid = d >> 6, lane = d & 63;
    if (lane == 0) { aS[wid] = s1; aQ[wid] = s2; }
    __syncthreads();
    float ts1 = aS[0] + aS[1] + aS[2];
    float ts2 = aQ[0] + aQ[1] + aQ[2];
    float mean = ts1 * (1.f / 192.f);
    float var  = ts2 * (1.f / 192.f) - mean * mean;
    float inv  = rsqrtf(var + 1e-5f);
    out[((size_t)b * L_ + p) * D_ + d] = (v - mean) * inv * gw[d] + gb[d];
}

// ---------------------------------------------------------------------------
extern "C" void kernel_launch(void* const* d_in, const int* in_sizes, int n_in,
                              void* d_out, int out_size, void* d_ws, size_t ws_size,
                              hipStream_t stream) {
    const float* x    = (const float*)d_in[0];
    const float* Wp   = (const float*)d_in[1];
    const float* dtw  = (const float*)d_in[2];
    const float* dtb  = (const float*)d_in[3];
    const float* Alog = (const float*)d_in[4];
    const float* Dsk  = (const float*)d_in[5];
    const float* gw   = (const float*)d_in[6];
    const float* gb   = (const float*)d_in[7];
    float* out = (float*)d_out;

    char* ws = (char*)d_ws;
    const size_t S1b = (size_t)B_ * L_ * D_ * 2;            // 12.6 MB (xp0b/xp1b)
    const size_t Sx  = (size_t)B_ * K_ * L_ * CP * 4;       // 21.0 MB (xdbl)
    const size_t Ss  = (size_t)B_ * K_ * NC_ * D_ * N_ * 2; // 12.6 MB (P/Hloc/Hin)
    const size_t Ssb = (size_t)B_ * K_ * L_ * D_ * 4;       // 50.3 MB (Sbuf f32)
    char* p = ws;
    bf16*  xp0b = (bf16*)p;   p += S1b;
    bf16*  xp1b = (bf16*)p;   p += S1b;
    float* xdbl = (float*)p;  p += Sx;
    bf16*  Pst  = (bf16*)p;   p += Ss;
    bf16*  Hloc = (bf16*)p;   p += Ss;
    bf16*  Hin  = (bf16*)p;   p += Ss;
    float* Sbuf = (float*)p;  p += Ssb;
    bf16*  ys   = (bf16*)p;   // 50.3 MB; total ~185 MB

    k_transpose<<<B_ * 6 * 128, 256, 0, stream>>>(x, xp0b, xp1b);
    k_proj<<<B_ * K_ * (L_ / 64), 256, 0, stream>>>(xp0b, xp1b, Wp, xdbl);
    k_scanA<<<B_ * K_ * NC_, 192, 0, stream>>>(xdbl, xp0b, xp1b, dtw, dtb, Alog, Dsk,
                                               Pst, Hloc, Sbuf, ys);
    k_pass2<<<(B_ * K_ * D_ * N_) / 256, 256, 0, stream>>>(Pst, Hloc, Hin);
    k_corr<<<B_ * K_ * NC_, 192, 0, stream>>>(xdbl, Sbuf, Alog, Hin, ys);
    k_merge_ln<<<B_ * L_, 192, 0, stream>>>(ys, gw, gb, out);
}

// Round 11
// 264.140 us; speedup vs baseline: 11.2110x; 1.0041x over previous
//
#include <hip/hip_runtime.h>
#include <hip/hip_bf16.h>

#define B_  8
#define D_  192
#define H_  64
#define W_  64
#define L_  4096
#define K_  4
#define N_  16
#define R_  6
#define C_  38   // R + 2N
#define CP  40   // padded x_dbl row (floats)
#define CL_ 64   // scan chunk length
#define NC_ 64   // number of chunks (L_/CL_)

using bf16 = __hip_bfloat16;
typedef float v2f __attribute__((ext_vector_type(2)));
typedef short v8s __attribute__((ext_vector_type(8)));   // 8 bf16 (4 VGPRs)
typedef float f32x4 __attribute__((ext_vector_type(4))); // MFMA acc

static __device__ __forceinline__ float softplus_f(float x) {
    return fmaxf(x, 0.f) + __logf(1.f + __expf(-fabsf(x)));
}
static __device__ __forceinline__ float bflo(unsigned u) {
    return __uint_as_float(u << 16);
}

// ---------------------------------------------------------------------------
// Kernel 1: transpose x (B,D,L) -> xp0b (B,L,D) row-major scan order and
// xp1b (B,L1,D) col-major order (l1 = w*H + h), bf16.
// ---------------------------------------------------------------------------
__global__ __launch_bounds__(256) void k_transpose(const float* __restrict__ x,
                                                   bf16* __restrict__ xp0b,
                                                   bf16* __restrict__ xp1b) {
    __shared__ float tile[32][33];
    int bi = blockIdx.x;
    int pg = bi & 127;          // L/32 tiles
    int dg = (bi >> 7) % 6;     // D/32 tiles
    int b  = bi / (128 * 6);
    int tx = threadIdx.x & 31;
    int ty = threadIdx.x >> 5;  // 0..7
    size_t xbase = (size_t)b * D_ * L_;
    #pragma unroll
    for (int i = 0; i < 4; i++) {
        int d = dg * 32 + ty + i * 8;
        tile[ty + i * 8][tx] = x[xbase + (size_t)d * L_ + pg * 32 + tx];
    }
    __syncthreads();
    #pragma unroll
    for (int i = 0; i < 4; i++) {
        int p = pg * 32 + ty + i * 8;
        float v = tile[tx][ty + i * 8];
        bf16 vb = __float2bfloat16(v);
        int d = dg * 32 + tx;
        xp0b[((size_t)b * L_ + p) * D_ + d] = vb;
        int hh = p >> 6, ww = p & 63;
        int r = ww * 64 + hh;   // l1 index
        xp1b[((size_t)b * L_ + r) * D_ + d] = vb;
    }
}

// ---------------------------------------------------------------------------
// Kernel 2 (MFMA): x_dbl[b,k,l,c] = sum_d xs[b,k,d,l] * W[k,c,d]
// ---------------------------------------------------------------------------
__global__ __launch_bounds__(256) void k_proj(const bf16* __restrict__ xp0b,
                                              const bf16* __restrict__ xp1b,
                                              const float* __restrict__ Wp,   // (K,38,192) f32
                                              float* __restrict__ xdbl) {     // (B,K,L,CP)
    __shared__ __align__(16) unsigned short xt[64 * 200];
    __shared__ __align__(16) unsigned short wt[48 * 200];
    int blk  = blockIdx.x;
    int tile = blk & 63;
    int bk   = blk >> 6;
    int k    = bk & 3;
    int b    = bk >> 2;
    const bf16* xpb = (k & 1) ? xp1b : xp0b;
    int g0 = (k < 2) ? tile * 64 : (L_ - 64 - tile * 64);

    unsigned* wtu = (unsigned*)wt;
    for (int i = threadIdx.x; i < 1000; i += 256) wtu[3800 + i] = 0u;
    const float2* wsrc = (const float2*)(Wp + (size_t)k * C_ * D_);
    for (int i = threadIdx.x; i < 3648; i += 256) {   // 38*96 float2
        float2 wv2 = wsrc[i];
        int c = i / 96, dp = i % 96;
        bf16 b0 = __float2bfloat16(wv2.x), b1 = __float2bfloat16(wv2.y);
        unsigned pack = ((unsigned)(*(unsigned short*)&b1) << 16) |
                        (unsigned)(*(unsigned short*)&b0);
        wtu[c * 100 + dp] = pack;
    }
    const uint4* src = (const uint4*)(xpb + ((size_t)b * L_ + g0) * D_);
    for (int i = threadIdx.x; i < 1536; i += 256) {
        uint4 v = src[i];
        int row = i / 24, cg = i % 24;
        int rr = (k < 2) ? row : 63 - row;
        *((uint4*)(xt + rr * 200 + cg * 8)) = v;
    }
    __syncthreads();

    int wv   = threadIdx.x >> 6;
    int lane = threadIdx.x & 63;
    int m0   = wv * 16;
    int mrow = lane & 15;
    int kq   = lane >> 4;

    f32x4 acc[3];
    #pragma unroll
    for (int nt = 0; nt < 3; nt++) acc[nt] = (f32x4){0.f, 0.f, 0.f, 0.f};

    const unsigned short* arow = xt + (m0 + mrow) * 200 + kq * 8;
    const unsigned short* brow = wt + mrow * 200 + kq * 8;
    #pragma unroll
    for (int kt = 0; kt < 6; kt++) {
        v8s af = *(const v8s*)(arow + kt * 32);
        #pragma unroll
        for (int nt = 0; nt < 3; nt++) {
            v8s bf = *(const v8s*)(brow + nt * 16 * 200 + kt * 32);
            acc[nt] = __builtin_amdgcn_mfma_f32_16x16x32_bf16(af, bf, acc[nt], 0, 0, 0);
        }
    }

    int l0g = tile * 64;
    #pragma unroll
    for (int nt = 0; nt < 3; nt++) {
        int c = nt * 16 + mrow;
        if (c < C_) {
            #pragma unroll
            for (int r = 0; r < 4; r++) {
                int m = m0 + kq * 4 + r;
                xdbl[((size_t)bk * L_ + l0g + m) * CP + c] = acc[nt][r];
            }
        }
    }
}

// ---------------------------------------------------------------------------
// Kernel 3 (scanA): ONE scan pass from h=0 per chunk. Emits
// y_local = C.h_local + Ds*u (bf16) and chunk summary P=exp(A*S_64), Hloc.
// No S store — k_corr recomputes S from xdbl (bit-identical f32 sequence).
// ---------------------------------------------------------------------------
__global__ __launch_bounds__(192) void k_scanA(const float* __restrict__ xdbl,
                                               const bf16* __restrict__ xp0b,
                                               const bf16* __restrict__ xp1b,
                                               const float* __restrict__ dtw,   // (K,D,R)
                                               const float* __restrict__ dtb,   // (K,D)
                                               const float* __restrict__ Alog,  // (K*D,N)
                                               const float* __restrict__ Dsk,   // (K*D,)
                                               bf16* __restrict__ Pst,
                                               bf16* __restrict__ Hloc,
                                               bf16* __restrict__ ys) {         // (B,K,L,D)
    __shared__ __align__(16) unsigned short ut[CL_ * D_];  // 24.6 KB
    int blk = blockIdx.x;
    int c   = blk & (NC_ - 1);
    int bk  = blk >> 6;
    int k   = bk & 3;
    int b   = bk >> 2;
    int d   = threadIdx.x;

    int l0 = c * CL_;
    const bf16* xpb = (k & 1) ? xp1b : xp0b;
    int base_lu = (k < 2) ? l0 : (L_ - CL_ - l0);
    {
        const uint4* usrc = (const uint4*)(xpb + ((size_t)b * L_ + base_lu) * D_);
        uint4* udst = (uint4*)ut;
        #pragma unroll
        for (int i = 0; i < 8; i++) udst[threadIdx.x + i * 192] = usrc[threadIdx.x + i * 192];
    }

    v2f A2[8];     // A * log2(e) pairs, for exp2
    #pragma unroll
    for (int i = 0; i < 8; i++) {
        A2[i].x = -__expf(Alog[((size_t)(k * D_ + d)) * N_ + 2*i])   * 1.44269504f;
        A2[i].y = -__expf(Alog[((size_t)(k * D_ + d)) * N_ + 2*i+1]) * 1.44269504f;
    }
    float wr[R_];
    #pragma unroll
    for (int r = 0; r < R_; r++) wr[r] = dtw[(k * D_ + d) * R_ + r];
    float bias = dtb[k * D_ + d];
    float DsV  = Dsk[k * D_ + d];

    v2f h[8];
    #pragma unroll
    for (int i = 0; i < 8; i++) { h[i].x = 0.f; h[i].y = 0.f; }
    float S = 0.f;
    const float* rb = xdbl + ((size_t)bk * L_ + l0) * CP;
    bf16* yp  = ys   + ((size_t)bk * L_ + l0) * D_ + d;

    int uidx  = ((k < 2) ? 0 : (CL_ - 1)) * D_ + d;
    int ustep = (k < 2) ? D_ : -D_;
    __syncthreads();

    #pragma unroll 2
    for (int s = 0; s < CL_; s++) {
        const float4* r4 = (const float4*)(rb + s * CP);   // block-uniform -> s_load
        float4 q0 = r4[0], q1 = r4[1], q2 = r4[2], q3 = r4[3], q4 = r4[4];
        float4 q5 = r4[5], q6 = r4[6], q7 = r4[7], q8 = r4[8], q9 = r4[9];
        float dpre = bias + wr[0]*q0.x + wr[1]*q0.y + wr[2]*q0.z + wr[3]*q0.w
                          + wr[4]*q1.x + wr[5]*q1.y;
        float delta = softplus_f(dpre);
        float u = bflo(ut[uidx]);  uidx += ustep;          // ds_read_u16
        float du = delta * u;
        S += delta;
        v2f Bv[8] = {{q1.z,q1.w},{q2.x,q2.y},{q2.z,q2.w},{q3.x,q3.y},
                     {q3.z,q3.w},{q4.x,q4.y},{q4.z,q4.w},{q5.x,q5.y}};
        v2f Cv[8] = {{q5.z,q5.w},{q6.x,q6.y},{q6.z,q6.w},{q7.x,q7.y},
                     {q7.z,q7.w},{q8.x,q8.y},{q8.z,q8.w},{q9.x,q9.y}};
        v2f y2; y2.x = 0.f; y2.y = 0.f;
        #pragma unroll
        for (int i = 0; i < 8; i++) {
            v2f t = A2[i] * delta;
            v2f dA;
            dA.x = __builtin_amdgcn_exp2f(t.x);
            dA.y = __builtin_amdgcn_exp2f(t.y);
            h[i] = dA * h[i] + Bv[i] * du;
            y2   = y2 + h[i] * Cv[i];
        }
        float y = y2.x + y2.y;
        *yp = __float2bfloat16(y + u * DsV);
        yp += D_;
    }
    size_t o = ((size_t)blk * D_ + d) * N_;   // blk == bk*NC_ + c
    #pragma unroll
    for (int i = 0; i < 8; i++) {
        v2f t = A2[i] * S;
        Pst[o + 2*i]   = __float2bfloat16(__builtin_amdgcn_exp2f(t.x));
        Pst[o + 2*i+1] = __float2bfloat16(__builtin_amdgcn_exp2f(t.y));
        Hloc[o + 2*i]   = __float2bfloat16(h[i].x);
        Hloc[o + 2*i+1] = __float2bfloat16(h[i].y);
    }
}

// ---------------------------------------------------------------------------
// Kernel 4 (pass 2): chunk-prefix scan over NC_ chunks per (b,k,d,n).
// ---------------------------------------------------------------------------
__global__ __launch_bounds__(256) void k_pass2(const bf16* __restrict__ Pst,
                                               const bf16* __restrict__ Hloc,
                                               bf16* __restrict__ Hin) {
    int idx = blockIdx.x * 256 + threadIdx.x;   // over B*K*D*N
    int bk  = idx / (D_ * N_);
    int dn  = idx % (D_ * N_);
    float hh = 0.f;
    for (int c = 0; c < NC_; c++) {
        size_t o = ((size_t)bk * NC_ + c) * (D_ * N_) + dn;
        Hin[o] = __float2bfloat16(hh);
        hh = __bfloat162float(Pst[o]) * hh + __bfloat162float(Hloc[o]);
    }
}

// ---------------------------------------------------------------------------
// Kernel 5 (corr): ys += C_l . (exp(A*S_l) * h_in). S is recomputed from
// xdbl's dt columns (scalar-prefetch path; bit-identical to scanA) — no
// per-step vector-load dependency. Per-wave ballot exits the dead tail
// (exp(A*S) < 2^-18) early, typically ~18-25 of 64 steps alive.
// ---------------------------------------------------------------------------
__global__ __launch_bounds__(192) void k_corr(const float* __restrict__ xdbl,
                                              const float* __restrict__ dtw,   // (K,D,R)
                                              const float* __restrict__ dtb,   // (K,D)
                                              const float* __restrict__ Alog,
                                              const bf16* __restrict__ Hin,
                                              bf16* __restrict__ ys) {
    int blk = blockIdx.x;
    int c   = blk & (NC_ - 1);
    if (c == 0) return;                        // h_in == 0 for first chunk
    int bk  = blk >> 6;
    int k   = bk & 3;
    int d   = threadIdx.x;

    float A2[N_];
    float aMax = -1e30f;
    #pragma unroll
    for (int n = 0; n < N_; n++) {
        A2[n] = -__expf(Alog[((size_t)(k * D_ + d)) * N_ + n]) * 1.44269504f;
        aMax = fmaxf(aMax, A2[n]);
    }
    float wr[R_];
    #pragma unroll
    for (int r = 0; r < R_; r++) wr[r] = dtw[(k * D_ + d) * R_ + r];
    float bias = dtb[k * D_ + d];

    float g[N_];
    size_t o = ((size_t)blk * D_ + d) * N_;
    #pragma unroll
    for (int n = 0; n < N_; n++) g[n] = __bfloat162float(Hin[o + n]);

    int l0 = c * CL_;
    const float* rb = xdbl + ((size_t)bk * L_ + l0) * CP;   // block-uniform
    bf16* yp = ys + ((size_t)bk * L_ + l0) * D_ + d;

    float S = 0.f;
    for (int s = 0; s < CL_; s++) {
        const float4* r4 = (const float4*)(rb + s * CP);    // s_load path
        float4 q0 = r4[0], q1 = r4[1];
        float dpre = bias + wr[0]*q0.x + wr[1]*q0.y + wr[2]*q0.z + wr[3]*q0.w
                          + wr[4]*q1.x + wr[5]*q1.y;
        S += softplus_f(dpre);                              // identical to scanA
        bool alive = (aMax * S > -18.f);       // 2^-18 ~ 4e-6: below bf16 noise
        if (__ballot(alive) == 0ull) break;
        const float4* c4 = (const float4*)(rb + s * CP + 20);  // C part
        float4 c5 = c4[0], c6 = c4[1], c7 = c4[2], c8 = c4[3], c9 = c4[4];
        float Cv[N_] = {c5.z,c5.w,c6.x,c6.y,c6.z,c6.w,c7.x,c7.y,
                        c7.z,c7.w,c8.x,c8.y,c8.z,c8.w,c9.x,c9.y};
        float acc = 0.f;
        #pragma unroll
        for (int n = 0; n < N_; n++) {
            float e = __builtin_amdgcn_exp2f(A2[n] * S);
            acc = fmaf(Cv[n], e * g[n], acc);
        }
        float y = __bfloat162float(*yp) + acc;
        *yp = __float2bfloat16(y);
        yp += D_;
    }
}

// ---------------------------------------------------------------------------
// Kernel 6: cross-merge (4 directions) + LayerNorm over D, output (B,H,W,D)
// ---------------------------------------------------------------------------
__global__ __launch_bounds__(192) void k_merge_ln(const bf16* __restrict__ ys,
                                                  const float* __restrict__ gw,
                                                  const float* __restrict__ gb,
                                                  float* __restrict__ out) {
    int p = blockIdx.x & (L_ - 1);
    int b = blockIdx.x >> 12;     // L_ = 4096
    int d = threadIdx.x;
    int hh = p >> 6, ww = p & 63;
    int l1 = ww * 64 + hh;
    size_t base = (size_t)b * K_ * L_ * D_;
    float v = __bfloat162float(ys[base + ((size_t)0 * L_ + p) * D_ + d])
            + __bfloat162float(ys[base + ((size_t)2 * L_ + (L_ - 1 - p)) * D_ + d])
            + __bfloat162float(ys[base + ((size_t)1 * L_ + l1) * D_ + d])
            + __bfloat162float(ys[base + ((size_t)3 * L_ + (L_ - 1 - l1)) * D_ + d]);
    float s1 = v, s2 = v * v;
    #pragma unroll
    for (int off = 32; off; off >>= 1) {
        s1 += __shfl_down(s1, off);
        s2 += __shfl_down(s2, off);
    }
    __shared__ float aS[3], aQ[3];
    int wid = d >> 6, lane = d & 63;
    if (lane == 0) { aS[wid] = s1; aQ[wid] = s2; }
    __syncthreads();
    float ts1 = aS[0] + aS[1] + aS[2];
    float ts2 = aQ[0] + aQ[1] + aQ[2];
    float mean = ts1 * (1.f / 192.f);
    float var  = ts2 * (1.f / 192.f) - mean * mean;
    float inv  = rsqrtf(var + 1e-5f);
    out[((size_t)b * L_ + p) * D_ + d] = (v - mean) * inv * gw[d] + gb[d];
}

// ---------------------------------------------------------------------------
extern "C" void kernel_launch(void* const* d_in, const int* in_sizes, int n_in,
                              void* d_out, int out_size, void* d_ws, size_t ws_size,
                              hipStream_t stream) {
    const float* x    = (const float*)d_in[0];
    const float* Wp   = (const float*)d_in[1];
    const float* dtw  = (const float*)d_in[2];
    const float* dtb  = (const float*)d_in[3];
    const float* Alog = (const float*)d_in[4];
    const float* Dsk  = (const float*)d_in[5];
    const float* gw   = (const float*)d_in[6];
    const float* gb   = (const float*)d_in[7];
    float* out = (float*)d_out;

    char* ws = (char*)d_ws;
    const size_t S1b = (size_t)B_ * L_ * D_ * 2;            // 12.6 MB (xp0b/xp1b)
    const size_t Sx  = (size_t)B_ * K_ * L_ * CP * 4;       // 21.0 MB (xdbl)
    const size_t Ss  = (size_t)B_ * K_ * NC_ * D_ * N_ * 2; // 12.6 MB (P/Hloc/Hin)
    char* p = ws;
    bf16*  xp0b = (bf16*)p;   p += S1b;
    bf16*  xp1b = (bf16*)p;   p += S1b;
    float* xdbl = (float*)p;  p += Sx;
    bf16*  Pst  = (bf16*)p;   p += Ss;
    bf16*  Hloc = (bf16*)p;   p += Ss;
    bf16*  Hin  = (bf16*)p;   p += Ss;
    bf16*  ys   = (bf16*)p;   // 50.3 MB; total ~135 MB

    k_transpose<<<B_ * 6 * 128, 256, 0, stream>>>(x, xp0b, xp1b);
    k_proj<<<B_ * K_ * (L_ / 64), 256, 0, stream>>>(xp0b, xp1b, Wp, xdbl);
    k_scanA<<<B_ * K_ * NC_, 192, 0, stream>>>(xdbl, xp0b, xp1b, dtw, dtb, Alog, Dsk,
                                               Pst, Hloc, ys);
    k_pass2<<<(B_ * K_ * D_ * N_) / 256, 256, 0, stream>>>(Pst, Hloc, Hin);
    k_corr<<<B_ * K_ * NC_, 192, 0, stream>>>(xdbl, dtw, dtb, Alog, Hin, ys);
    k_merge_ln<<<B_ * L_, 192, 0, stream>>>(ys, gw, gb, out);
}